// Round 2
// baseline (1356.549 us; speedup 1.0000x reference)
//
#include <hip/hip_runtime.h>
#include <hip/hip_bf16.h>
#include <math.h>

#define H 128
#define CDIV(a,b) (((a)+(b)-1)/(b))

__device__ __forceinline__ float wave_reduce_sum(float v){
  #pragma unroll
  for (int off = 32; off > 0; off >>= 1) v += __shfl_down(v, off, 64);
  return v;
}

// ---------------------------------------------------------------------------
// Precompute all small derived quantities:
//  sm[0..127]   qd1v = c1v_Wd @ c1v_ad      (for sdst of layer1 v-direction)
//  sm[128..255] qd1r = c1r_Wd @ c1r_ad
//  sm[256..383] qd2v = c2v_W  @ c2v_ad
//  sm[384..511] qd2r = c2r_W  @ c2r_ad
//  sm[512..575] layer1 edge tables: sacc[20] strans[20] sseason[20] wn[3] cb[1]
//  sm[576..639] layer2 edge tables
//  sm[640..767] biascat = [bmu | bls]
//  sm[768..17151] Wcat[128][128] = [Wmu | Wls]
// ---------------------------------------------------------------------------
__global__ void k_precompute(const float* c1v_Wd, const float* c1v_ad,
                             const float* c1r_Wd, const float* c1r_ad,
                             const float* c2v_W,  const float* c2v_ad,
                             const float* c2r_W,  const float* c2r_ad,
                             const float* c1v_We, const float* c1v_ae,
                             const float* c2v_We, const float* c2v_ae,
                             const float* Weout,  const float* beout,
                             const float* emb_acc, const float* emb_trans, const float* emb_season,
                             const float* Wnum, const float* bnum,
                             const float* Wmu, const float* Wls, const float* bmu, const float* bls,
                             float* sm)
{
  __shared__ float ws[H], vs[H];
  const int t = threadIdx.x;  // blockDim = 128
  float a0 = 0.f, a1 = 0.f, a2 = 0.f, a3 = 0.f;
  for (int j = 0; j < H; ++j){
    a0 += c1v_Wd[t*H+j] * c1v_ad[j];
    a1 += c1r_Wd[t*H+j] * c1r_ad[j];
    a2 += c2v_W [t*H+j] * c2v_ad[j];
    a3 += c2r_W [t*H+j] * c2r_ad[j];
  }
  sm[0*H+t] = a0; sm[1*H+t] = a1; sm[2*H+t] = a2; sm[3*H+t] = a3;

  for (int layer = 0; layer < 2; ++layer){
    const float* We = layer ? c2v_We : c1v_We;
    const float* ae = layer ? c2v_ae : c1v_ae;
    float w = 0.f;
    for (int j = 0; j < H; ++j) w += We[t*H+j] * ae[j];
    ws[t] = w;
    __syncthreads();
    float v = 0.f;
    for (int j = 0; j < H; ++j) v += Weout[t*H+j] * ws[j];
    vs[t] = v;
    __syncthreads();
    float* tab = sm + 512 + layer*64;
    if (t < 20){
      float s1 = 0.f, s2 = 0.f, s3 = 0.f;
      for (int i = 0; i < 32; ++i){
        s1 += emb_acc   [t*32+i] * vs[i];
        s2 += emb_trans [t*32+i] * vs[32+i];
        s3 += emb_season[t*32+i] * vs[64+i];
      }
      tab[t] = s1; tab[20+t] = s2; tab[40+t] = s3;
    }
    if (t < 3){
      float s = 0.f;
      for (int i = 0; i < 32; ++i) s += Wnum[t*32+i] * vs[96+i];
      tab[60+t] = s;
    }
    if (t == 0){
      float s = 0.f;
      for (int j = 0; j < H; ++j)  s += beout[j] * ws[j];
      for (int i = 0; i < 32; ++i) s += bnum[i] * vs[96+i];
      tab[63] = s;
    }
    __syncthreads();
  }
  float* Wcat = sm + 768;
  float* bcat = sm + 640;
  for (int i = t; i < 8192; i += 128){
    int h = i >> 6, o = i & 63;
    Wcat[h*H + o]      = Wmu[h*64 + o];
    Wcat[h*H + 64 + o] = Wls[h*64 + o];
  }
  if (t < 64){ bcat[t] = bmu[t]; bcat[64+t] = bls[t]; }
}

// h_user = user_emb + x_user @ Wuf + buf   (3 features)
__global__ void k_enc_user(const float* __restrict__ emb, const float* __restrict__ x,
                           const float* __restrict__ Wf, const float* __restrict__ b,
                           float* __restrict__ out, int N)
{
  int i = blockIdx.x * blockDim.x + threadIdx.x;
  if (i >= N * H) return;
  int u = i >> 7, h = i & 127;
  out[i] = emb[i] + b[h] + x[u*3]*Wf[h] + x[u*3+1]*Wf[H+h] + x[u*3+2]*Wf[2*H+h];
}

// h_dest = dest_emb + x_dest @ Wdf + bdf   (1 feature)
__global__ void k_enc_dest(const float* __restrict__ emb, const float* __restrict__ x,
                           const float* __restrict__ Wf, const float* __restrict__ b,
                           float* __restrict__ out, int N)
{
  int i = blockIdx.x * blockDim.x + threadIdx.x;
  if (i >= N * H) return;
  int d = i >> 7, h = i & 127;
  out[i] = emb[i] + b[h] + x[d]*Wf[h];
}

// out[n] = mat[n,:] . vec   (one wave per row)
__global__ void k_row_dot(const float* __restrict__ mat, const float* __restrict__ vec,
                          float* __restrict__ out, int N)
{
  int wid  = (blockIdx.x * blockDim.x + threadIdx.x) >> 6;
  int lane = threadIdx.x & 63;
  if (wid >= N) return;
  const float* row = mat + (size_t)wid * H;
  float p = row[lane]*vec[lane] + row[64+lane]*vec[64+lane];
  p = wave_reduce_sum(p);
  if (lane == 0) out[wid] = p;
}

// C[N,128] = A[N,128] @ W[128,128] (+bias). Columns 0..63 -> out0 (stride ld0),
// 64..127 -> out1 (stride ld1). 256 threads, 32 rows/block, 4x4 register tile.
__global__ __launch_bounds__(256) void k_gemm128(const float* __restrict__ A,
                                                 const float* __restrict__ W,
                                                 const float* __restrict__ bias,
                                                 float* __restrict__ out0, float* __restrict__ out1,
                                                 int ld0, int ld1, int N)
{
  __shared__ float Ws[64][128];
  __shared__ float Xs[32][64];
  const int tid = threadIdx.x;
  const int rb  = blockIdx.x * 32;
  const int tc  = tid & 31, tr = tid >> 5;
  const int c0  = tc * 4;
  float C[4][4] = {};
  for (int k0 = 0; k0 < 128; k0 += 64){
    for (int i = tid; i < 2048; i += 256){           // W chunk: 64x128
      int k = i >> 5, c4 = i & 31;
      *(float4*)&Ws[k][c4*4] = *(const float4*)&W[(size_t)(k0+k)*128 + c4*4];
    }
    for (int i = tid; i < 512; i += 256){            // X chunk: 32x64
      int r = i >> 4, c4 = i & 15;
      int row = rb + r;
      float4 v = make_float4(0.f, 0.f, 0.f, 0.f);
      if (row < N) v = *(const float4*)&A[(size_t)row*128 + k0 + c4*4];
      *(float4*)&Xs[r][c4*4] = v;
    }
    __syncthreads();
    #pragma unroll 8
    for (int k = 0; k < 64; ++k){
      float4 wv = *(float4*)&Ws[k][c0];
      #pragma unroll
      for (int i = 0; i < 4; ++i){
        float xv = Xs[tr*4+i][k];
        C[i][0] += xv*wv.x; C[i][1] += xv*wv.y; C[i][2] += xv*wv.z; C[i][3] += xv*wv.w;
      }
    }
    __syncthreads();
  }
  #pragma unroll
  for (int i = 0; i < 4; ++i){
    int row = rb + tr*4 + i;
    if (row >= N) continue;
    #pragma unroll
    for (int j = 0; j < 4; ++j){
      int c = c0 + j;
      float v = C[i][j];
      if (bias) v += bias[c];
      if (c < 64) out0[(size_t)row*ld0 + c]      = v;
      else        out1[(size_t)row*ld1 + (c-64)] = v;
    }
  }
}

// alpha for v-direction (has edge-feature term folded into tables)
__global__ void k_alpha_v(const int* __restrict__ esrc, const int* __restrict__ edst,
                          const int* __restrict__ ecat, const float* __restrict__ enum_,
                          const float* __restrict__ sU, const float* __restrict__ sD,
                          const float* __restrict__ tab, float* __restrict__ alpha, int E)
{
  int e = blockIdx.x * blockDim.x + threadIdx.x;
  if (e >= E) return;
  float a = sU[esrc[e]] + sD[edst[e]]
          + tab[ecat[e*3]] + tab[20 + ecat[e*3+1]] + tab[40 + ecat[e*3+2]]
          + enum_[e*3]*tab[60] + enum_[e*3+1]*tab[61] + enum_[e*3+2]*tab[62] + tab[63];
  alpha[e] = a > 0.f ? a : 0.2f * a;
}

// alpha for r-direction: a = ssrc[edge_dst[e]] + sdst[edge_src[e]]
__global__ void k_alpha_r(const int* __restrict__ egrp, const int* __restrict__ eoth,
                          const float* __restrict__ sOth, const float* __restrict__ sGrp,
                          float* __restrict__ alpha, int E)
{
  int e = blockIdx.x * blockDim.x + threadIdx.x;
  if (e >= E) return;
  float a = sOth[eoth[e]] + sGrp[egrp[e]];
  alpha[e] = a > 0.f ? a : 0.2f * a;
}

__global__ void k_zero_int(int* p, int n){
  int i = blockIdx.x * blockDim.x + threadIdx.x;
  if (i < n) p[i] = 0;
}

__global__ void k_count(const int* __restrict__ idx, int* __restrict__ cnt, int E){
  int e = blockIdx.x * blockDim.x + threadIdx.x;
  if (e < E) atomicAdd(&cnt[idx[e]], 1);
}

// single-block exclusive scan: offs[0]=0, offs[i+1]=offs[i]+cnt[i]; cursor[i]=offs[i]
// cursor may alias cnt (read-before-write per element).
__global__ __launch_bounds__(1024) void k_scan(const int* __restrict__ cnt, int* __restrict__ offs,
                                               int* __restrict__ cursor, int n)
{
  __shared__ int wsum[16];
  __shared__ int carry_s;
  const int tid = threadIdx.x, lane = tid & 63, wid = tid >> 6;
  if (tid == 0){ carry_s = 0; offs[0] = 0; }
  __syncthreads();
  for (int base = 0; base < n; base += 1024){
    int i = base + tid;
    int v = (i < n) ? cnt[i] : 0;
    int inc = v;
    #pragma unroll
    for (int d = 1; d < 64; d <<= 1){
      int t2 = __shfl_up(inc, d, 64);
      if (lane >= d) inc += t2;
    }
    if (lane == 63) wsum[wid] = inc;
    __syncthreads();
    if (tid < 16){
      int x = wsum[tid];
      #pragma unroll
      for (int d = 1; d < 16; d <<= 1){
        int t2 = __shfl_up(x, d, 16);
        if (tid >= d) x += t2;
      }
      wsum[tid] = x;                   // inclusive per-wave sums
    }
    __syncthreads();
    int wex  = (wid > 0) ? wsum[wid-1] : 0;
    int excl = carry_s + wex + (inc - v);
    if (i < n){ offs[i+1] = excl + v; cursor[i] = excl; }
    __syncthreads();
    if (tid == 0) carry_s += wsum[15];
    __syncthreads();
  }
}

__global__ void k_scatter(const int* __restrict__ idx, int* __restrict__ cursor,
                          int* __restrict__ eidx, int E){
  int e = blockIdx.x * blockDim.x + threadIdx.x;
  if (e < E){
    int p = atomicAdd(&cursor[idx[e]], 1);
    eidx[p] = e;
  }
}

// Segment softmax + weighted gather + bias + ReLU. One block (128 thr) per dst node.
__global__ __launch_bounds__(128) void k_agg(const int* __restrict__ offs, const int* __restrict__ eidx,
                                             const int* __restrict__ other, const float* __restrict__ alpha,
                                             const float* __restrict__ xs, const float* __restrict__ bias,
                                             float* __restrict__ out)
{
  __shared__ float red[128];
  const int d = blockIdx.x;
  const int tid = threadIdx.x;
  const int beg = offs[d], end = offs[d+1];

  float m = -1e30f;
  for (int i = beg + tid; i < end; i += 128) m = fmaxf(m, alpha[eidx[i]]);
  red[tid] = m; __syncthreads();
  #pragma unroll
  for (int s = 64; s > 0; s >>= 1){
    if (tid < s) red[tid] = fmaxf(red[tid], red[tid+s]);
    __syncthreads();
  }
  m = red[0]; __syncthreads();

  float s = 0.f;
  for (int i = beg + tid; i < end; i += 128) s += __expf(alpha[eidx[i]] - m);
  red[tid] = s; __syncthreads();
  #pragma unroll
  for (int st = 64; st > 0; st >>= 1){
    if (tid < st) red[tid] += red[tid+st];
    __syncthreads();
  }
  s = red[0];

  const float inv = 1.f / (s + 1e-16f);
  float acc = 0.f;
  for (int i = beg; i < end; ++i){
    int e = eidx[i];
    float w = __expf(alpha[e] - m) * inv;
    acc += w * xs[(size_t)other[e]*H + tid];
  }
  out[(size_t)d*H + tid] = fmaxf(acc + bias[tid], 0.f);
}

// pred[l] = mu_u[label_src[l],:] . mu_d[label_dst[l],:]   (one wave per label, O=64)
__global__ void k_pred(const int* __restrict__ ls, const int* __restrict__ ld,
                       const float* __restrict__ mu_u, const float* __restrict__ mu_d,
                       float* __restrict__ pred, int L)
{
  int wid  = (blockIdx.x * blockDim.x + threadIdx.x) >> 6;
  int lane = threadIdx.x & 63;
  if (wid >= L) return;
  float p = mu_u[(size_t)ls[wid]*64 + lane] * mu_d[(size_t)ld[wid]*64 + lane];
  p = wave_reduce_sum(p);
  if (lane == 0) pred[wid] = p;
}

extern "C" void kernel_launch(void* const* d_in, const int* in_sizes, int n_in,
                              void* d_out, int out_size, void* d_ws, size_t ws_size,
                              hipStream_t stream)
{
  (void)n_in; (void)out_size; (void)ws_size;
  const float* x_user    = (const float*)d_in[0];
  const float* x_dest    = (const float*)d_in[1];
  const int*   edge_src  = (const int*)d_in[2];
  const int*   edge_dst  = (const int*)d_in[3];
  const int*   eattr_cat = (const int*)d_in[4];
  const float* eattr_num = (const float*)d_in[5];
  const int*   label_src = (const int*)d_in[6];
  const int*   label_dst = (const int*)d_in[7];
  const float* user_emb  = (const float*)d_in[8];
  const float* dest_emb  = (const float*)d_in[9];
  const float* Wuf = (const float*)d_in[10]; const float* buf_ = (const float*)d_in[11];
  const float* Wdf = (const float*)d_in[12]; const float* bdf  = (const float*)d_in[13];
  const float* emb_acc    = (const float*)d_in[14];
  const float* emb_trans  = (const float*)d_in[15];
  const float* emb_season = (const float*)d_in[16];
  const float* Wnum = (const float*)d_in[17]; const float* bnum  = (const float*)d_in[18];
  const float* Weout = (const float*)d_in[19]; const float* beout = (const float*)d_in[20];
  const float* c1v_Ws = (const float*)d_in[21]; const float* c1v_Wd = (const float*)d_in[22];
  const float* c1v_as = (const float*)d_in[23]; const float* c1v_ad = (const float*)d_in[24];
  const float* c1v_We = (const float*)d_in[25]; const float* c1v_ae = (const float*)d_in[26];
  const float* c1v_b  = (const float*)d_in[27];
  const float* c1r_Ws = (const float*)d_in[28]; const float* c1r_Wd = (const float*)d_in[29];
  const float* c1r_as = (const float*)d_in[30]; const float* c1r_ad = (const float*)d_in[31];
  const float* c1r_b  = (const float*)d_in[32];
  const float* c2v_W  = (const float*)d_in[33]; const float* c2v_as = (const float*)d_in[34];
  const float* c2v_ad = (const float*)d_in[35]; const float* c2v_We = (const float*)d_in[36];
  const float* c2v_ae = (const float*)d_in[37]; const float* c2v_b  = (const float*)d_in[38];
  const float* c2r_W  = (const float*)d_in[39]; const float* c2r_as = (const float*)d_in[40];
  const float* c2r_ad = (const float*)d_in[41]; const float* c2r_b  = (const float*)d_in[42];
  const float* Wmu = (const float*)d_in[43]; const float* bmu = (const float*)d_in[44];
  const float* Wls = (const float*)d_in[45]; const float* bls = (const float*)d_in[46];

  const int U = in_sizes[0] / 3;
  const int D = in_sizes[1];
  const int E = in_sizes[2];
  const int L = in_sizes[6];
  const int O = 64;

  // ---- workspace layout (floats, 16B-aligned chunks) ----
  float* fw = (float*)d_ws;
  size_t off = 0;
  auto falloc = [&](size_t n)->float*{ float* p = fw + off; off += (n + 3) & ~(size_t)3; return p; };
  float* A    = falloc((size_t)U * H);   // h_user -> hu -> zu
  float* BIG  = falloc((size_t)U * H);   // xs1v / xs2v
  float* Bd   = falloc((size_t)D * H);   // h_dest -> hd -> zd
  float* SM   = falloc((size_t)D * H);   // xs1r / xs2r
  float* alV  = falloc(E);
  float* alR  = falloc(E);
  float* sUa  = falloc(U);               // ssrc (U-indexed, v-direction)
  float* sUb  = falloc(U);               // sdst (U-indexed, r-direction)
  float* sDa  = falloc(D);               // sdst (D-indexed, v-direction)
  float* sDb  = falloc(D);               // ssrc (D-indexed, r-direction)
  float* sml  = falloc(17152);
  int* iw = (int*)(fw + off);
  size_t ioff = 0;
  auto ialloc = [&](size_t n)->int*{ int* p = iw + ioff; ioff += (n + 3) & ~(size_t)3; return p; };
  int* cntD  = ialloc(D);     // counts, then cursor
  int* offsD = ialloc((size_t)D + 1);
  int* cntU  = ialloc(U);
  int* offsU = ialloc((size_t)U + 1);
  int* eidxD = ialloc(E);
  int* eidxU = ialloc(E);

  float* outp = (float*)d_out;
  float* pred = outp;
  float* mu_u = outp + L;
  float* mu_d = mu_u + (size_t)U * O;
  float* ls_u = mu_d + (size_t)D * O;
  float* ls_d = ls_u + (size_t)U * O;

  // ---- small precompute + node encoders ----
  hipLaunchKernelGGL(k_precompute, dim3(1), dim3(128), 0, stream,
                     c1v_Wd, c1v_ad, c1r_Wd, c1r_ad, c2v_W, c2v_ad, c2r_W, c2r_ad,
                     c1v_We, c1v_ae, c2v_We, c2v_ae, Weout, beout,
                     emb_acc, emb_trans, emb_season, Wnum, bnum, Wmu, Wls, bmu, bls, sml);
  hipLaunchKernelGGL(k_enc_user, dim3(CDIV((size_t)U*H, 256)), dim3(256), 0, stream,
                     user_emb, x_user, Wuf, buf_, A, U);
  hipLaunchKernelGGL(k_enc_dest, dim3(CDIV((size_t)D*H, 256)), dim3(256), 0, stream,
                     dest_emb, x_dest, Wdf, bdf, Bd, D);

  // ---- CSRs (grouped by edge_dst -> D segments; by edge_src -> U segments) ----
  hipLaunchKernelGGL(k_zero_int, dim3(CDIV(D,256)), dim3(256), 0, stream, cntD, D);
  hipLaunchKernelGGL(k_zero_int, dim3(CDIV(U,256)), dim3(256), 0, stream, cntU, U);
  hipLaunchKernelGGL(k_count, dim3(CDIV(E,256)), dim3(256), 0, stream, edge_dst, cntD, E);
  hipLaunchKernelGGL(k_count, dim3(CDIV(E,256)), dim3(256), 0, stream, edge_src, cntU, E);
  hipLaunchKernelGGL(k_scan, dim3(1), dim3(1024), 0, stream, cntD, offsD, cntD, D);
  hipLaunchKernelGGL(k_scan, dim3(1), dim3(1024), 0, stream, cntU, offsU, cntU, U);
  hipLaunchKernelGGL(k_scatter, dim3(CDIV(E,256)), dim3(256), 0, stream, edge_dst, cntD, eidxD, E);
  hipLaunchKernelGGL(k_scatter, dim3(CDIV(E,256)), dim3(256), 0, stream, edge_src, cntU, eidxU, E);

  // ---- layer 1 ----
  hipLaunchKernelGGL(k_row_dot, dim3(CDIV((size_t)D*64,256)), dim3(256), 0, stream, Bd, sml+0,   sDa, D); // sdst1v
  hipLaunchKernelGGL(k_row_dot, dim3(CDIV((size_t)U*64,256)), dim3(256), 0, stream, A,  sml+128, sUb, U); // sdst1r
  hipLaunchKernelGGL(k_gemm128, dim3(CDIV(U,32)), dim3(256), 0, stream, A,  c1v_Ws, (const float*)nullptr, BIG, BIG+64, 128, 128, U);
  hipLaunchKernelGGL(k_row_dot, dim3(CDIV((size_t)U*64,256)), dim3(256), 0, stream, BIG, c1v_as, sUa, U); // ssrc1v
  hipLaunchKernelGGL(k_gemm128, dim3(CDIV(D,32)), dim3(256), 0, stream, Bd, c1r_Ws, (const float*)nullptr, SM, SM+64, 128, 128, D);
  hipLaunchKernelGGL(k_row_dot, dim3(CDIV((size_t)D*64,256)), dim3(256), 0, stream, SM, c1r_as, sDb, D);  // ssrc1r
  hipLaunchKernelGGL(k_alpha_v, dim3(CDIV(E,256)), dim3(256), 0, stream,
                     edge_src, edge_dst, eattr_cat, eattr_num, sUa, sDa, sml+512, alV, E);
  hipLaunchKernelGGL(k_alpha_r, dim3(CDIV(E,256)), dim3(256), 0, stream,
                     edge_src, edge_dst, sDb, sUb, alR, E);
  hipLaunchKernelGGL(k_agg, dim3(D), dim3(128), 0, stream, offsD, eidxD, edge_src, alV, BIG, c1v_b, Bd); // hd
  hipLaunchKernelGGL(k_agg, dim3(U), dim3(128), 0, stream, offsU, eidxU, edge_dst, alR, SM,  c1r_b, A);  // hu

  // ---- layer 2 ----
  hipLaunchKernelGGL(k_row_dot, dim3(CDIV((size_t)D*64,256)), dim3(256), 0, stream, Bd, sml+256, sDa, D); // sdst2v
  hipLaunchKernelGGL(k_row_dot, dim3(CDIV((size_t)U*64,256)), dim3(256), 0, stream, A,  sml+384, sUb, U); // sdst2r
  hipLaunchKernelGGL(k_gemm128, dim3(CDIV(U,32)), dim3(256), 0, stream, A,  c2v_W, (const float*)nullptr, BIG, BIG+64, 128, 128, U);
  hipLaunchKernelGGL(k_row_dot, dim3(CDIV((size_t)U*64,256)), dim3(256), 0, stream, BIG, c2v_as, sUa, U); // ssrc2v
  hipLaunchKernelGGL(k_gemm128, dim3(CDIV(D,32)), dim3(256), 0, stream, Bd, c2r_W, (const float*)nullptr, SM, SM+64, 128, 128, D);
  hipLaunchKernelGGL(k_row_dot, dim3(CDIV((size_t)D*64,256)), dim3(256), 0, stream, SM, c2r_as, sDb, D);  // ssrc2r
  hipLaunchKernelGGL(k_alpha_v, dim3(CDIV(E,256)), dim3(256), 0, stream,
                     edge_src, edge_dst, eattr_cat, eattr_num, sUa, sDa, sml+576, alV, E);
  hipLaunchKernelGGL(k_alpha_r, dim3(CDIV(E,256)), dim3(256), 0, stream,
                     edge_src, edge_dst, sDb, sUb, alR, E);
  hipLaunchKernelGGL(k_agg, dim3(D), dim3(128), 0, stream, offsD, eidxD, edge_src, alV, BIG, c2v_b, Bd); // zd
  hipLaunchKernelGGL(k_agg, dim3(U), dim3(128), 0, stream, offsU, eidxU, edge_dst, alR, SM,  c2r_b, A);  // zu

  // ---- heads + decode ----
  hipLaunchKernelGGL(k_gemm128, dim3(CDIV(U,32)), dim3(256), 0, stream, A,  sml+768, sml+640, mu_u, ls_u, 64, 64, U);
  hipLaunchKernelGGL(k_gemm128, dim3(CDIV(D,32)), dim3(256), 0, stream, Bd, sml+768, sml+640, mu_d, ls_d, 64, 64, D);
  hipLaunchKernelGGL(k_pred, dim3(CDIV((size_t)L*64,256)), dim3(256), 0, stream,
                     label_src, label_dst, mu_u, mu_d, pred, L);
}

// Round 3
// 916.831 us; speedup vs baseline: 1.4796x; 1.4796x over previous
//
#include <hip/hip_runtime.h>
#include <hip/hip_bf16.h>
#include <math.h>

#define H 128
#define CDIV(a,b) (((a)+(b)-1)/(b))

__device__ __forceinline__ float wave_reduce_sum(float v){
  #pragma unroll
  for (int off = 32; off > 0; off >>= 1) v += __shfl_down(v, off, 64);
  return v;
}
__device__ __forceinline__ float wave_reduce_max(float v){
  #pragma unroll
  for (int off = 32; off > 0; off >>= 1) v = fmaxf(v, __shfl_xor(v, off, 64));
  return v;
}

// ---------------------------------------------------------------------------
// sm layout (floats):
//  [0..127]    qd1v = c1v_Wd @ c1v_ad
//  [128..255]  qd1r = c1r_Wd @ c1r_ad
//  [256..383]  qd2v = c2v_W  @ c2v_ad
//  [384..511]  qd2r = c2r_W  @ c2r_ad
//  [512..575]  layer1 edge tables: sacc[20] strans[20] sseason[20] wn[3] cb[1]
//  [576..639]  layer2 edge tables
//  [640..767]  biascat = [bmu | bls]
//  [768..17151] Wcat[128][128] = [Wmu | Wls]
// blocks: 0..3 qd dots, 4 edge tables, 5..11 Wcat copy
// ---------------------------------------------------------------------------
__global__ __launch_bounds__(128) void k_precompute(
    const float* c1v_Wd, const float* c1v_ad,
    const float* c1r_Wd, const float* c1r_ad,
    const float* c2v_W,  const float* c2v_ad,
    const float* c2r_W,  const float* c2r_ad,
    const float* c1v_We, const float* c1v_ae,
    const float* c2v_We, const float* c2v_ae,
    const float* Weout,  const float* beout,
    const float* emb_acc, const float* emb_trans, const float* emb_season,
    const float* Wnum, const float* bnum,
    const float* Wmu, const float* Wls, const float* bmu, const float* bls,
    float* sm)
{
  const int b = blockIdx.x, t = threadIdx.x;
  if (b < 4){
    const float* M; const float* a;
    if      (b == 0){ M = c1v_Wd; a = c1v_ad; }
    else if (b == 1){ M = c1r_Wd; a = c1r_ad; }
    else if (b == 2){ M = c2v_W;  a = c2v_ad; }
    else            { M = c2r_W;  a = c2r_ad; }
    float s = 0.f;
    for (int j = 0; j < H; ++j) s += M[t*H+j] * a[j];
    sm[b*H + t] = s;
  } else if (b == 4){
    __shared__ float ws[H], vs[H];
    for (int layer = 0; layer < 2; ++layer){
      const float* We = layer ? c2v_We : c1v_We;
      const float* ae = layer ? c2v_ae : c1v_ae;
      float w = 0.f;
      for (int j = 0; j < H; ++j) w += We[t*H+j] * ae[j];
      ws[t] = w;
      __syncthreads();
      float v = 0.f;
      for (int j = 0; j < H; ++j) v += Weout[t*H+j] * ws[j];
      vs[t] = v;
      __syncthreads();
      float* tab = sm + 512 + layer*64;
      if (t < 20){
        float s1 = 0.f, s2 = 0.f, s3 = 0.f;
        for (int i = 0; i < 32; ++i){
          s1 += emb_acc   [t*32+i] * vs[i];
          s2 += emb_trans [t*32+i] * vs[32+i];
          s3 += emb_season[t*32+i] * vs[64+i];
        }
        tab[t] = s1; tab[20+t] = s2; tab[40+t] = s3;
      }
      if (t < 3){
        float s = 0.f;
        for (int i = 0; i < 32; ++i) s += Wnum[t*32+i] * vs[96+i];
        tab[60+t] = s;
      }
      if (t == 0){
        float s = 0.f;
        for (int j = 0; j < H; ++j)  s += beout[j] * ws[j];
        for (int i = 0; i < 32; ++i) s += bnum[i] * vs[96+i];
        tab[63] = s;
      }
      __syncthreads();
    }
  } else {
    float* Wcat = sm + 768;
    for (int i = (b-5)*128 + t; i < 8192; i += 7*128){
      int h = i >> 6, o = i & 63;
      Wcat[h*H + o]      = Wmu[h*64 + o];
      Wcat[h*H + 64 + o] = Wls[h*64 + o];
    }
    if (b == 5) sm[640 + t] = (t < 64) ? bmu[t] : bls[t-64];
  }
}

// wave-per-row encoders, fused sdst dot: sout[r] = h[r,:] . qd
__global__ __launch_bounds__(256) void k_enc_user(
    const float* __restrict__ emb, const float* __restrict__ x,
    const float* __restrict__ Wf, const float* __restrict__ b,
    const float* __restrict__ qd, float* __restrict__ out,
    float* __restrict__ sout, int N)
{
  int w = (blockIdx.x*blockDim.x + threadIdx.x) >> 6;
  int lane = threadIdx.x & 63;
  if (w >= N) return;
  const float2* emb2 = (const float2*)emb;
  const float2* Wf2  = (const float2*)Wf;
  float2 e  = emb2[(size_t)w*64 + lane];
  float x0 = x[w*3], x1 = x[w*3+1], x2 = x[w*3+2];
  float2 w0 = Wf2[lane], w1 = Wf2[64+lane], w2 = Wf2[128+lane];
  float2 bb = ((const float2*)b)[lane];
  float h0 = e.x + bb.x + x0*w0.x + x1*w1.x + x2*w2.x;
  float h1 = e.y + bb.y + x0*w0.y + x1*w1.y + x2*w2.y;
  ((float2*)out)[(size_t)w*64 + lane] = make_float2(h0, h1);
  float2 q = ((const float2*)qd)[lane];
  float p = wave_reduce_sum(h0*q.x + h1*q.y);
  if (lane == 0) sout[w] = p;
}

__global__ __launch_bounds__(256) void k_enc_dest(
    const float* __restrict__ emb, const float* __restrict__ x,
    const float* __restrict__ Wf, const float* __restrict__ b,
    const float* __restrict__ qd, float* __restrict__ out,
    float* __restrict__ sout, int N)
{
  int w = (blockIdx.x*blockDim.x + threadIdx.x) >> 6;
  int lane = threadIdx.x & 63;
  if (w >= N) return;
  float2 e  = ((const float2*)emb)[(size_t)w*64 + lane];
  float x0 = x[w];
  float2 w0 = ((const float2*)Wf)[lane];
  float2 bb = ((const float2*)b)[lane];
  float h0 = e.x + bb.x + x0*w0.x;
  float h1 = e.y + bb.y + x0*w0.y;
  ((float2*)out)[(size_t)w*64 + lane] = make_float2(h0, h1);
  float2 q = ((const float2*)qd)[lane];
  float p = wave_reduce_sum(h0*q.x + h1*q.y);
  if (lane == 0) sout[w] = p;
}

// C[N,128] = A[N,128] @ W[128,128] (+bias). cols 0..63 -> out0, 64..127 -> out1.
// 256 threads, 64 rows/block, 4x8 register tile. Optional fused row-dot:
// sout[r] = (A@W)[r,:] . asv  (pre-bias).
__global__ __launch_bounds__(256) void k_gemm128(
    const float* __restrict__ A, const float* __restrict__ W,
    const float* __restrict__ bias, const float* __restrict__ asv,
    float* __restrict__ sout,
    float* __restrict__ out0, float* __restrict__ out1,
    int ld0, int ld1, int N)
{
  __shared__ float Ws[64][128];
  __shared__ float Xs[64][132];
  __shared__ float red[64][17];
  const int tid = threadIdx.x;
  const int rb  = blockIdx.x * 64;
  const int tc  = tid & 15, tr = tid >> 4;   // tc 0..15 (8 cols), tr 0..15 (4 rows)
  const int c0  = tc * 8;
  float C[4][8] = {};
  for (int k0 = 0; k0 < 128; k0 += 64){
    for (int i = tid; i < 2048; i += 256){            // W chunk 64x128
      int k = i >> 5, c4 = i & 31;
      *(float4*)&Ws[k][c4*4] = *(const float4*)&W[(size_t)(k0+k)*128 + c4*4];
    }
    for (int i = tid; i < 1024; i += 256){            // X chunk 64 rows x 64 k
      int r = i >> 4, kg = i & 15;
      int row = rb + r;
      float4 v = make_float4(0.f,0.f,0.f,0.f);
      if (row < N) v = *(const float4*)&A[(size_t)row*128 + k0 + kg*4];
      *(float4*)&Xs[r][kg*4] = v;
    }
    __syncthreads();
    #pragma unroll 4
    for (int k = 0; k < 64; ++k){
      float4 w0 = *(float4*)&Ws[k][c0];
      float4 w1 = *(float4*)&Ws[k][c0+4];
      #pragma unroll
      for (int i = 0; i < 4; ++i){
        float x = Xs[tr*4+i][k];
        C[i][0] += x*w0.x; C[i][1] += x*w0.y; C[i][2] += x*w0.z; C[i][3] += x*w0.w;
        C[i][4] += x*w1.x; C[i][5] += x*w1.y; C[i][6] += x*w1.z; C[i][7] += x*w1.w;
      }
    }
    __syncthreads();
  }
  float4 b0 = make_float4(0,0,0,0), b1 = make_float4(0,0,0,0);
  if (bias){ b0 = *(const float4*)&bias[c0]; b1 = *(const float4*)&bias[c0+4]; }
  float4 a0 = make_float4(0,0,0,0), a1 = make_float4(0,0,0,0);
  if (asv){ a0 = *(const float4*)&asv[c0]; a1 = *(const float4*)&asv[c0+4]; }
  #pragma unroll
  for (int i = 0; i < 4; ++i){
    int row = rb + tr*4 + i;
    float s = 0.f;
    if (row < N){
      float4 v0 = make_float4(C[i][0]+b0.x, C[i][1]+b0.y, C[i][2]+b0.z, C[i][3]+b0.w);
      float4 v1 = make_float4(C[i][4]+b1.x, C[i][5]+b1.y, C[i][6]+b1.z, C[i][7]+b1.w);
      if (c0 < 64){
        *(float4*)&out0[(size_t)row*ld0 + c0]     = v0;
        *(float4*)&out0[(size_t)row*ld0 + c0 + 4] = v1;
      } else {
        *(float4*)&out1[(size_t)row*ld1 + (c0-64)]     = v0;
        *(float4*)&out1[(size_t)row*ld1 + (c0-64) + 4] = v1;
      }
      if (asv){
        s = C[i][0]*a0.x + C[i][1]*a0.y + C[i][2]*a0.z + C[i][3]*a0.w
          + C[i][4]*a1.x + C[i][5]*a1.y + C[i][6]*a1.z + C[i][7]*a1.w;
      }
    }
    if (asv) red[tr*4+i][tc] = s;
  }
  if (asv){
    __syncthreads();
    if (tid < 64){
      int row = rb + tid;
      if (row < N){
        float t = 0.f;
        #pragma unroll
        for (int j = 0; j < 16; ++j) t += red[tid][j];
        sout[row] = t;
      }
    }
  }
}

// fused alpha for both directions; scattered write to sorted positions
__global__ __launch_bounds__(256) void k_alpha_both(
    const int* __restrict__ esrc, const int* __restrict__ edst,
    const int* __restrict__ ecat, const float* __restrict__ enum_,
    const float* __restrict__ sUa, const float* __restrict__ sDa,
    const float* __restrict__ sDb, const float* __restrict__ sUb,
    const float* __restrict__ tab,
    const int* __restrict__ slotD, const int* __restrict__ slotU,
    float* __restrict__ alVs, float* __restrict__ alRs, int E)
{
  int e = blockIdx.x * blockDim.x + threadIdx.x;
  if (e >= E) return;
  int s = esrc[e], d = edst[e];
  float av = sUa[s] + sDa[d]
           + tab[ecat[e*3]] + tab[20 + ecat[e*3+1]] + tab[40 + ecat[e*3+2]]
           + enum_[e*3]*tab[60] + enum_[e*3+1]*tab[61] + enum_[e*3+2]*tab[62] + tab[63];
  av = av > 0.f ? av : 0.2f * av;
  alVs[slotD[e]] = av;
  float ar = sDb[d] + sUb[s];
  ar = ar > 0.f ? ar : 0.2f * ar;
  alRs[slotU[e]] = ar;
}

__global__ void k_zero2(int* a, int na, int* b, int nb){
  int i = blockIdx.x * blockDim.x + threadIdx.x;
  if (i < na) a[i] = 0;
  else if (i - na < nb) b[i - na] = 0;
}

__global__ void k_count_both(const int* __restrict__ esrc, const int* __restrict__ edst,
                             int* __restrict__ cntU, int* __restrict__ cntD, int E){
  int e = blockIdx.x * blockDim.x + threadIdx.x;
  if (e < E){ atomicAdd(&cntU[esrc[e]], 1); atomicAdd(&cntD[edst[e]], 1); }
}

// 3-phase scan. phase1: per-1024-block inclusive scan -> offs[i+1], block totals -> bsum
__global__ __launch_bounds__(1024) void k_scan1(const int* __restrict__ cnt,
                                                int* __restrict__ offs,
                                                int* __restrict__ bsum, int n)
{
  __shared__ int wsum[16];
  const int tid = threadIdx.x, lane = tid & 63, wid = tid >> 6;
  const int i = blockIdx.x * 1024 + tid;
  int v = (i < n) ? cnt[i] : 0;
  int inc = v;
  #pragma unroll
  for (int d = 1; d < 64; d <<= 1){
    int t2 = __shfl_up(inc, d, 64);
    if (lane >= d) inc += t2;
  }
  if (lane == 63) wsum[wid] = inc;
  __syncthreads();
  if (tid < 16){
    int x = wsum[tid];
    #pragma unroll
    for (int d = 1; d < 16; d <<= 1){
      int t2 = __shfl_up(x, d, 16);
      if (tid >= d) x += t2;
    }
    wsum[tid] = x;
  }
  __syncthreads();
  int incl = ((wid > 0) ? wsum[wid-1] : 0) + inc;
  if (i < n) offs[i+1] = incl;
  if (tid == 0) bsum[blockIdx.x] = wsum[15];
}

// phase2: single-block exclusive scan of block sums (nb <= 1024)
__global__ __launch_bounds__(1024) void k_scan2(int* __restrict__ bsum, int nb)
{
  __shared__ int wsum[16];
  const int tid = threadIdx.x, lane = tid & 63, wid = tid >> 6;
  int v = (tid < nb) ? bsum[tid] : 0;
  int inc = v;
  #pragma unroll
  for (int d = 1; d < 64; d <<= 1){
    int t2 = __shfl_up(inc, d, 64);
    if (lane >= d) inc += t2;
  }
  if (lane == 63) wsum[wid] = inc;
  __syncthreads();
  if (tid < 16){
    int x = wsum[tid];
    #pragma unroll
    for (int d = 1; d < 16; d <<= 1){
      int t2 = __shfl_up(x, d, 16);
      if (tid >= d) x += t2;
    }
    wsum[tid] = x;
  }
  __syncthreads();
  int excl = ((wid > 0) ? wsum[wid-1] : 0) + inc - v;
  if (tid < nb) bsum[tid] = excl;
}

// phase3: add block prefix, produce final offs[i+1] and cursor[i]=offs[i]
__global__ void k_scan3(const int* __restrict__ cnt, const int* __restrict__ bsum,
                        int* __restrict__ offs, int* __restrict__ cursor, int n)
{
  int i = blockIdx.x * blockDim.x + threadIdx.x;
  if (i >= n) return;
  int v = offs[i+1] + bsum[i >> 10];
  offs[i+1] = v;
  cursor[i] = v - cnt[i];
  if (i == 0) offs[0] = 0;
}

// scatter into both CSRs: record slot (edge -> sorted pos) and sorted "other" node
__global__ void k_scatter_both(const int* __restrict__ esrc, const int* __restrict__ edst,
                               int* __restrict__ curU, int* __restrict__ curD,
                               int* __restrict__ slotU, int* __restrict__ slotD,
                               int* __restrict__ srtOU, int* __restrict__ srtOD, int E)
{
  int e = blockIdx.x * blockDim.x + threadIdx.x;
  if (e >= E) return;
  int s = esrc[e], d = edst[e];
  int pD = atomicAdd(&curD[d], 1);
  slotD[e] = pD; srtOD[pD] = s;
  int pU = atomicAdd(&curU[s], 1);
  slotU[e] = pU; srtOU[pU] = d;
}

// Segment softmax + weighted gather + bias + ReLU. One WAVE per dst node.
// Optional fused dot: sout[d] = out[d,:] . qd
__global__ __launch_bounds__(256) void k_agg(
    const int* __restrict__ offs, const int* __restrict__ srt_other,
    const float* __restrict__ al, const float* __restrict__ xs,
    const float* __restrict__ bias, float* __restrict__ out,
    const float* __restrict__ qd, float* __restrict__ sout, int N)
{
  int w = (blockIdx.x*blockDim.x + threadIdx.x) >> 6;
  int lane = threadIdx.x & 63;
  if (w >= N) return;
  const int beg = offs[w], end = offs[w+1];

  float m = -1e30f;
  for (int i = beg + lane; i < end; i += 64) m = fmaxf(m, al[i]);
  m = wave_reduce_max(m);
  float s = 0.f;
  for (int i = beg + lane; i < end; i += 64) s += __expf(al[i] - m);
  s = wave_reduce_sum(s);
  s = __shfl(s, 0, 64);
  const float inv = 1.f / (s + 1e-16f);

  float a0 = 0.f, a1 = 0.f;
  const float2* xs2 = (const float2*)xs;
  for (int base = beg; base < end; base += 64){
    int nn = min(64, end - base);
    int o_l = 0; float w_l = 0.f;
    if (base + lane < end){
      o_l = srt_other[base + lane];
      w_l = __expf(al[base + lane] - m) * inv;
    }
    for (int j = 0; j < nn; ++j){
      int   oo = __shfl(o_l, j, 64);
      float ww = __shfl(w_l, j, 64);
      float2 v = xs2[(size_t)oo*64 + lane];
      a0 += ww * v.x; a1 += ww * v.y;
    }
  }
  float2 bb = ((const float2*)bias)[lane];
  float r0 = fmaxf(a0 + bb.x, 0.f);
  float r1 = fmaxf(a1 + bb.y, 0.f);
  ((float2*)out)[(size_t)w*64 + lane] = make_float2(r0, r1);
  if (qd){
    float2 q = ((const float2*)qd)[lane];
    float p = wave_reduce_sum(r0*q.x + r1*q.y);
    if (lane == 0) sout[w] = p;
  }
}

// pred[l] = mu_u[label_src[l],:] . mu_d[label_dst[l],:]  (wave per label, O=64)
__global__ void k_pred(const int* __restrict__ ls, const int* __restrict__ ld,
                       const float* __restrict__ mu_u, const float* __restrict__ mu_d,
                       float* __restrict__ pred, int L)
{
  int wid  = (blockIdx.x * blockDim.x + threadIdx.x) >> 6;
  int lane = threadIdx.x & 63;
  if (wid >= L) return;
  float p = mu_u[(size_t)ls[wid]*64 + lane] * mu_d[(size_t)ld[wid]*64 + lane];
  p = wave_reduce_sum(p);
  if (lane == 0) pred[wid] = p;
}

extern "C" void kernel_launch(void* const* d_in, const int* in_sizes, int n_in,
                              void* d_out, int out_size, void* d_ws, size_t ws_size,
                              hipStream_t stream)
{
  (void)n_in; (void)out_size; (void)ws_size;
  const float* x_user    = (const float*)d_in[0];
  const float* x_dest    = (const float*)d_in[1];
  const int*   edge_src  = (const int*)d_in[2];
  const int*   edge_dst  = (const int*)d_in[3];
  const int*   eattr_cat = (const int*)d_in[4];
  const float* eattr_num = (const float*)d_in[5];
  const int*   label_src = (const int*)d_in[6];
  const int*   label_dst = (const int*)d_in[7];
  const float* user_emb  = (const float*)d_in[8];
  const float* dest_emb  = (const float*)d_in[9];
  const float* Wuf = (const float*)d_in[10]; const float* buf_ = (const float*)d_in[11];
  const float* Wdf = (const float*)d_in[12]; const float* bdf  = (const float*)d_in[13];
  const float* emb_acc    = (const float*)d_in[14];
  const float* emb_trans  = (const float*)d_in[15];
  const float* emb_season = (const float*)d_in[16];
  const float* Wnum = (const float*)d_in[17]; const float* bnum  = (const float*)d_in[18];
  const float* Weout = (const float*)d_in[19]; const float* beout = (const float*)d_in[20];
  const float* c1v_Ws = (const float*)d_in[21]; const float* c1v_Wd = (const float*)d_in[22];
  const float* c1v_as = (const float*)d_in[23]; const float* c1v_ad = (const float*)d_in[24];
  const float* c1v_We = (const float*)d_in[25]; const float* c1v_ae = (const float*)d_in[26];
  const float* c1v_b  = (const float*)d_in[27];
  const float* c1r_Ws = (const float*)d_in[28]; const float* c1r_Wd = (const float*)d_in[29];
  const float* c1r_as = (const float*)d_in[30]; const float* c1r_ad = (const float*)d_in[31];
  const float* c1r_b  = (const float*)d_in[32];
  const float* c2v_W  = (const float*)d_in[33]; const float* c2v_as = (const float*)d_in[34];
  const float* c2v_ad = (const float*)d_in[35]; const float* c2v_We = (const float*)d_in[36];
  const float* c2v_ae = (const float*)d_in[37]; const float* c2v_b  = (const float*)d_in[38];
  const float* c2r_W  = (const float*)d_in[39]; const float* c2r_as = (const float*)d_in[40];
  const float* c2r_ad = (const float*)d_in[41]; const float* c2r_b  = (const float*)d_in[42];
  const float* Wmu = (const float*)d_in[43]; const float* bmu = (const float*)d_in[44];
  const float* Wls = (const float*)d_in[45]; const float* bls = (const float*)d_in[46];

  const int U = in_sizes[0] / 3;
  const int D = in_sizes[1];
  const int E = in_sizes[2];
  const int L = in_sizes[6];
  const int O = 64;
  const int nbD = CDIV(D, 1024), nbU = CDIV(U, 1024);

  // ---- workspace layout ----
  float* fw = (float*)d_ws;
  size_t off = 0;
  auto falloc = [&](size_t n)->float*{ float* p = fw + off; off += (n + 3) & ~(size_t)3; return p; };
  float* A    = falloc((size_t)U * H);   // h_user -> hu -> zu
  float* BIG  = falloc((size_t)U * H);   // xs (v-direction payloads)
  float* Bd   = falloc((size_t)D * H);   // h_dest -> hd -> zd
  float* SM   = falloc((size_t)D * H);   // xs (r-direction payloads)
  float* alVs = falloc(E);               // sorted alpha, D-CSR order
  float* alRs = falloc(E);               // sorted alpha, U-CSR order
  float* sUa  = falloc(U);               // ssrc (U-indexed, v-dir)
  float* sUb  = falloc(U);               // sdst (U-indexed, r-dir)
  float* sDa  = falloc(D);               // sdst (D-indexed, v-dir)
  float* sDb  = falloc(D);               // ssrc (D-indexed, r-dir)
  float* sml  = falloc(17152);
  int* iw = (int*)(fw + off);
  size_t ioff = 0;
  auto ialloc = [&](size_t n)->int*{ int* p = iw + ioff; ioff += (n + 3) & ~(size_t)3; return p; };
  int* cntD  = ialloc(D);
  int* curD  = ialloc(D);
  int* offsD = ialloc((size_t)D + 1);
  int* cntU  = ialloc(U);
  int* curU  = ialloc(U);
  int* offsU = ialloc((size_t)U + 1);
  int* slotD = ialloc(E);
  int* slotU = ialloc(E);
  int* srtOD = ialloc(E);
  int* srtOU = ialloc(E);
  int* bsumD = ialloc(1024);
  int* bsumU = ialloc(1024);

  float* outp = (float*)d_out;
  float* pred = outp;
  float* mu_u = outp + L;
  float* mu_d = mu_u + (size_t)U * O;
  float* ls_u = mu_d + (size_t)D * O;
  float* ls_d = ls_u + (size_t)U * O;

  // ---- precompute + encoders (fused layer-1 sdst dots) ----
  hipLaunchKernelGGL(k_precompute, dim3(12), dim3(128), 0, stream,
                     c1v_Wd, c1v_ad, c1r_Wd, c1r_ad, c2v_W, c2v_ad, c2r_W, c2r_ad,
                     c1v_We, c1v_ae, c2v_We, c2v_ae, Weout, beout,
                     emb_acc, emb_trans, emb_season, Wnum, bnum, Wmu, Wls, bmu, bls, sml);
  hipLaunchKernelGGL(k_enc_user, dim3(CDIV(U,4)), dim3(256), 0, stream,
                     user_emb, x_user, Wuf, buf_, sml+128, A, sUb, U);
  hipLaunchKernelGGL(k_enc_dest, dim3(CDIV(D,4)), dim3(256), 0, stream,
                     dest_emb, x_dest, Wdf, bdf, sml+0, Bd, sDa, D);

  // ---- CSR build ----
  hipLaunchKernelGGL(k_zero2, dim3(CDIV(U+D,256)), dim3(256), 0, stream, cntU, U, cntD, D);
  hipLaunchKernelGGL(k_count_both, dim3(CDIV(E,256)), dim3(256), 0, stream,
                     edge_src, edge_dst, cntU, cntD, E);
  hipLaunchKernelGGL(k_scan1, dim3(nbD), dim3(1024), 0, stream, cntD, offsD, bsumD, D);
  hipLaunchKernelGGL(k_scan1, dim3(nbU), dim3(1024), 0, stream, cntU, offsU, bsumU, U);
  hipLaunchKernelGGL(k_scan2, dim3(1), dim3(1024), 0, stream, bsumD, nbD);
  hipLaunchKernelGGL(k_scan2, dim3(1), dim3(1024), 0, stream, bsumU, nbU);
  hipLaunchKernelGGL(k_scan3, dim3(CDIV(D,256)), dim3(256), 0, stream, cntD, bsumD, offsD, curD, D);
  hipLaunchKernelGGL(k_scan3, dim3(CDIV(U,256)), dim3(256), 0, stream, cntU, bsumU, offsU, curU, U);
  hipLaunchKernelGGL(k_scatter_both, dim3(CDIV(E,256)), dim3(256), 0, stream,
                     edge_src, edge_dst, curU, curD, slotU, slotD, srtOU, srtOD, E);

  // ---- layer 1 ----
  hipLaunchKernelGGL(k_gemm128, dim3(CDIV(U,64)), dim3(256), 0, stream,
                     A,  c1v_Ws, (const float*)nullptr, c1v_as, sUa, BIG, BIG+64, 128, 128, U);
  hipLaunchKernelGGL(k_gemm128, dim3(CDIV(D,64)), dim3(256), 0, stream,
                     Bd, c1r_Ws, (const float*)nullptr, c1r_as, sDb, SM, SM+64, 128, 128, D);
  hipLaunchKernelGGL(k_alpha_both, dim3(CDIV(E,256)), dim3(256), 0, stream,
                     edge_src, edge_dst, eattr_cat, eattr_num, sUa, sDa, sDb, sUb,
                     sml+512, slotD, slotU, alVs, alRs, E);
  hipLaunchKernelGGL(k_agg, dim3(CDIV(D,4)), dim3(256), 0, stream,
                     offsD, srtOD, alVs, BIG, c1v_b, Bd, sml+256, sDa, D);   // hd (+sdst2v)
  hipLaunchKernelGGL(k_agg, dim3(CDIV(U,4)), dim3(256), 0, stream,
                     offsU, srtOU, alRs, SM, c1r_b, A, sml+384, sUb, U);     // hu (+sdst2r)

  // ---- layer 2 ----
  hipLaunchKernelGGL(k_gemm128, dim3(CDIV(U,64)), dim3(256), 0, stream,
                     A,  c2v_W, (const float*)nullptr, c2v_as, sUa, BIG, BIG+64, 128, 128, U);
  hipLaunchKernelGGL(k_gemm128, dim3(CDIV(D,64)), dim3(256), 0, stream,
                     Bd, c2r_W, (const float*)nullptr, c2r_as, sDb, SM, SM+64, 128, 128, D);
  hipLaunchKernelGGL(k_alpha_both, dim3(CDIV(E,256)), dim3(256), 0, stream,
                     edge_src, edge_dst, eattr_cat, eattr_num, sUa, sDa, sDb, sUb,
                     sml+576, slotD, slotU, alVs, alRs, E);
  hipLaunchKernelGGL(k_agg, dim3(CDIV(D,4)), dim3(256), 0, stream,
                     offsD, srtOD, alVs, BIG, c2v_b, Bd, (const float*)nullptr, (float*)nullptr, D); // zd
  hipLaunchKernelGGL(k_agg, dim3(CDIV(U,4)), dim3(256), 0, stream,
                     offsU, srtOU, alRs, SM, c2r_b, A, (const float*)nullptr, (float*)nullptr, U);   // zu

  // ---- heads + decode ----
  hipLaunchKernelGGL(k_gemm128, dim3(CDIV(U,64)), dim3(256), 0, stream,
                     A,  sml+768, sml+640, (const float*)nullptr, (float*)nullptr, mu_u, ls_u, 64, 64, U);
  hipLaunchKernelGGL(k_gemm128, dim3(CDIV(D,64)), dim3(256), 0, stream,
                     Bd, sml+768, sml+640, (const float*)nullptr, (float*)nullptr, mu_d, ls_d, 64, 64, D);
  hipLaunchKernelGGL(k_pred, dim3(CDIV((size_t)L*64,256)), dim3(256), 0, stream,
                     label_src, label_dst, mu_u, mu_d, pred, L);
}

// Round 5
// 875.482 us; speedup vs baseline: 1.5495x; 1.0472x over previous
//
#include <hip/hip_runtime.h>
#include <hip/hip_bf16.h>
#include <math.h>

#define H 128
#define CDIV(a,b) (((a)+(b)-1)/(b))

__device__ __forceinline__ float wave_reduce_sum(float v){
  #pragma unroll
  for (int off = 32; off > 0; off >>= 1) v += __shfl_down(v, off, 64);
  return v;
}

// merge per-lane online-softmax states (m,s) across the wave
__device__ __forceinline__ void wave_merge_ms(float& m, float& s){
  #pragma unroll
  for (int off = 32; off > 0; off >>= 1){
    float m2 = __shfl_xor(m, off, 64);
    float s2 = __shfl_xor(s, off, 64);
    float mn = fmaxf(m, m2);
    s = s*__expf(m - mn) + s2*__expf(m2 - mn);
    m = mn;
  }
}

// ---------------------------------------------------------------------------
// sm layout (floats):
//  [0..127]    qd1v = c1v_Wd @ c1v_ad
//  [128..255]  qd1r = c1r_Wd @ c1r_ad
//  [256..383]  qd2v = c2v_W  @ c2v_ad
//  [384..511]  qd2r = c2r_W  @ c2r_ad
//  [512..575]  layer1 edge tables: sacc[20] strans[20] sseason[20] wn[3] cb[1]
//  [576..639]  layer2 edge tables
//  [640..767]  biascat = [bmu | bls]
//  [768..17151] Wcat[128][128] = [Wmu | Wls]
// ---------------------------------------------------------------------------
__global__ __launch_bounds__(128) void k_precompute(
    const float* c1v_Wd, const float* c1v_ad,
    const float* c1r_Wd, const float* c1r_ad,
    const float* c2v_W,  const float* c2v_ad,
    const float* c2r_W,  const float* c2r_ad,
    const float* c1v_We, const float* c1v_ae,
    const float* c2v_We, const float* c2v_ae,
    const float* Weout,  const float* beout,
    const float* emb_acc, const float* emb_trans, const float* emb_season,
    const float* Wnum, const float* bnum,
    const float* Wmu, const float* Wls, const float* bmu, const float* bls,
    float* sm)
{
  const int b = blockIdx.x, t = threadIdx.x;
  if (b < 4){
    const float* M; const float* a;
    if      (b == 0){ M = c1v_Wd; a = c1v_ad; }
    else if (b == 1){ M = c1r_Wd; a = c1r_ad; }
    else if (b == 2){ M = c2v_W;  a = c2v_ad; }
    else            { M = c2r_W;  a = c2r_ad; }
    float s = 0.f;
    for (int j = 0; j < H; ++j) s += M[t*H+j] * a[j];
    sm[b*H + t] = s;
  } else if (b == 4){
    __shared__ float ws[H], vs[H];
    for (int layer = 0; layer < 2; ++layer){
      const float* We = layer ? c2v_We : c1v_We;
      const float* ae = layer ? c2v_ae : c1v_ae;
      float w = 0.f;
      for (int j = 0; j < H; ++j) w += We[t*H+j] * ae[j];
      ws[t] = w;
      __syncthreads();
      float v = 0.f;
      for (int j = 0; j < H; ++j) v += Weout[t*H+j] * ws[j];
      vs[t] = v;
      __syncthreads();
      float* tab = sm + 512 + layer*64;
      if (t < 20){
        float s1 = 0.f, s2 = 0.f, s3 = 0.f;
        for (int i = 0; i < 32; ++i){
          s1 += emb_acc   [t*32+i] * vs[i];
          s2 += emb_trans [t*32+i] * vs[32+i];
          s3 += emb_season[t*32+i] * vs[64+i];
        }
        tab[t] = s1; tab[20+t] = s2; tab[40+t] = s3;
      }
      if (t < 3){
        float s = 0.f;
        for (int i = 0; i < 32; ++i) s += Wnum[t*32+i] * vs[96+i];
        tab[60+t] = s;
      }
      if (t == 0){
        float s = 0.f;
        for (int j = 0; j < H; ++j)  s += beout[j] * ws[j];
        for (int i = 0; i < 32; ++i) s += bnum[i] * vs[96+i];
        tab[63] = s;
      }
      __syncthreads();
    }
  } else {
    float* Wcat = sm + 768;
    for (int i = (b-5)*128 + t; i < 8192; i += 7*128){
      int h = i >> 6, o = i & 63;
      Wcat[h*H + o]      = Wmu[h*64 + o];
      Wcat[h*H + 64 + o] = Wls[h*64 + o];
    }
    if (b == 5) sm[640 + t] = (t < 64) ? bmu[t] : bls[t-64];
  }
}

// wave-per-row encoders, fused sdst dot: sout[r] = h[r,:] . qd
__global__ __launch_bounds__(256) void k_enc_user(
    const float* __restrict__ emb, const float* __restrict__ x,
    const float* __restrict__ Wf, const float* __restrict__ b,
    const float* __restrict__ qd, float* __restrict__ out,
    float* __restrict__ sout, int N)
{
  int w = (blockIdx.x*blockDim.x + threadIdx.x) >> 6;
  int lane = threadIdx.x & 63;
  if (w >= N) return;
  float2 e  = ((const float2*)emb)[(size_t)w*64 + lane];
  float x0 = x[w*3], x1 = x[w*3+1], x2 = x[w*3+2];
  float2 w0 = ((const float2*)Wf)[lane];
  float2 w1 = ((const float2*)Wf)[64+lane];
  float2 w2 = ((const float2*)Wf)[128+lane];
  float2 bb = ((const float2*)b)[lane];
  float h0 = e.x + bb.x + x0*w0.x + x1*w1.x + x2*w2.x;
  float h1 = e.y + bb.y + x0*w0.y + x1*w1.y + x2*w2.y;
  ((float2*)out)[(size_t)w*64 + lane] = make_float2(h0, h1);
  float2 q = ((const float2*)qd)[lane];
  float p = wave_reduce_sum(h0*q.x + h1*q.y);
  if (lane == 0) sout[w] = p;
}

__global__ __launch_bounds__(256) void k_enc_dest(
    const float* __restrict__ emb, const float* __restrict__ x,
    const float* __restrict__ Wf, const float* __restrict__ b,
    const float* __restrict__ qd, float* __restrict__ out,
    float* __restrict__ sout, int N)
{
  int w = (blockIdx.x*blockDim.x + threadIdx.x) >> 6;
  int lane = threadIdx.x & 63;
  if (w >= N) return;
  float2 e  = ((const float2*)emb)[(size_t)w*64 + lane];
  float x0 = x[w];
  float2 w0 = ((const float2*)Wf)[lane];
  float2 bb = ((const float2*)b)[lane];
  float h0 = e.x + bb.x + x0*w0.x;
  float h1 = e.y + bb.y + x0*w0.y;
  ((float2*)out)[(size_t)w*64 + lane] = make_float2(h0, h1);
  float2 q = ((const float2*)qd)[lane];
  float p = wave_reduce_sum(h0*q.x + h1*q.y);
  if (lane == 0) sout[w] = p;
}

// C[N,128] = A[N,128] @ W[128,128] (+bias). cols 0..63 -> out0, 64..127 -> out1.
// 256 threads, 64 rows/block, 4x8 register tile. Optional fused row-dot:
// sout[r] = (A@W)[r,:] . asv  (pre-bias).
__global__ __launch_bounds__(256) void k_gemm128(
    const float* __restrict__ A, const float* __restrict__ W,
    const float* __restrict__ bias, const float* __restrict__ asv,
    float* __restrict__ sout,
    float* __restrict__ out0, float* __restrict__ out1,
    int ld0, int ld1, int N)
{
  __shared__ float Ws[64][128];
  __shared__ float Xs[64][132];
  __shared__ float red[64][17];
  const int tid = threadIdx.x;
  const int rb  = blockIdx.x * 64;
  const int tc  = tid & 15, tr = tid >> 4;
  const int c0  = tc * 8;
  float C[4][8] = {};
  for (int k0 = 0; k0 < 128; k0 += 64){
    for (int i = tid; i < 2048; i += 256){            // W chunk 64x128
      int k = i >> 5, c4 = i & 31;
      *(float4*)&Ws[k][c4*4] = *(const float4*)&W[(size_t)(k0+k)*128 + c4*4];
    }
    for (int i = tid; i < 1024; i += 256){            // X chunk 64 rows x 64 k
      int r = i >> 4, kg = i & 15;
      int row = rb + r;
      float4 v = make_float4(0.f,0.f,0.f,0.f);
      if (row < N) v = *(const float4*)&A[(size_t)row*128 + k0 + kg*4];
      *(float4*)&Xs[r][kg*4] = v;
    }
    __syncthreads();
    #pragma unroll 4
    for (int k = 0; k < 64; ++k){
      float4 w0 = *(float4*)&Ws[k][c0];
      float4 w1 = *(float4*)&Ws[k][c0+4];
      #pragma unroll
      for (int i = 0; i < 4; ++i){
        float x = Xs[tr*4+i][k];
        C[i][0] += x*w0.x; C[i][1] += x*w0.y; C[i][2] += x*w0.z; C[i][3] += x*w0.w;
        C[i][4] += x*w1.x; C[i][5] += x*w1.y; C[i][6] += x*w1.z; C[i][7] += x*w1.w;
      }
    }
    __syncthreads();
  }
  float4 b0 = make_float4(0,0,0,0), b1 = make_float4(0,0,0,0);
  if (bias){ b0 = *(const float4*)&bias[c0]; b1 = *(const float4*)&bias[c0+4]; }
  float4 a0 = make_float4(0,0,0,0), a1 = make_float4(0,0,0,0);
  if (asv){ a0 = *(const float4*)&asv[c0]; a1 = *(const float4*)&asv[c0+4]; }
  #pragma unroll
  for (int i = 0; i < 4; ++i){
    int row = rb + tr*4 + i;
    float s = 0.f;
    if (row < N){
      float4 v0 = make_float4(C[i][0]+b0.x, C[i][1]+b0.y, C[i][2]+b0.z, C[i][3]+b0.w);
      float4 v1 = make_float4(C[i][4]+b1.x, C[i][5]+b1.y, C[i][6]+b1.z, C[i][7]+b1.w);
      if (c0 < 64){
        *(float4*)&out0[(size_t)row*ld0 + c0]     = v0;
        *(float4*)&out0[(size_t)row*ld0 + c0 + 4] = v1;
      } else {
        *(float4*)&out1[(size_t)row*ld1 + (c0-64)]     = v0;
        *(float4*)&out1[(size_t)row*ld1 + (c0-64) + 4] = v1;
      }
      if (asv){
        s = C[i][0]*a0.x + C[i][1]*a0.y + C[i][2]*a0.z + C[i][3]*a0.w
          + C[i][4]*a1.x + C[i][5]*a1.y + C[i][6]*a1.z + C[i][7]*a1.w;
      }
    }
    if (asv) red[tr*4+i][tc] = s;
  }
  if (asv){
    __syncthreads();
    if (tid < 64){
      int row = rb + tid;
      if (row < N){
        float t = 0.f;
        #pragma unroll
        for (int j = 0; j < 16; ++j) t += red[tid][j];
        sout[row] = t;
      }
    }
  }
}

__global__ void k_zero2(int* a, int na, int* b, int nb){
  int i = blockIdx.x * blockDim.x + threadIdx.x;
  if (i < na) a[i] = 0;
  else if (i - na < nb) b[i - na] = 0;
}

__global__ void k_count_both(const int* __restrict__ esrc, const int* __restrict__ edst,
                             int* __restrict__ cntU, int* __restrict__ cntD, int E){
  int e = blockIdx.x * blockDim.x + threadIdx.x;
  if (e < E){ atomicAdd(&cntU[esrc[e]], 1); atomicAdd(&cntD[edst[e]], 1); }
}

// 3-phase scan. phase1: per-1024-block inclusive scan -> offs[i+1], block totals -> bsum
__global__ __launch_bounds__(1024) void k_scan1(const int* __restrict__ cnt,
                                                int* __restrict__ offs,
                                                int* __restrict__ bsum, int n)
{
  __shared__ int wsum[16];
  const int tid = threadIdx.x, lane = tid & 63, wid = tid >> 6;
  const int i = blockIdx.x * 1024 + tid;
  int v = (i < n) ? cnt[i] : 0;
  int inc = v;
  #pragma unroll
  for (int d = 1; d < 64; d <<= 1){
    int t2 = __shfl_up(inc, d, 64);
    if (lane >= d) inc += t2;
  }
  if (lane == 63) wsum[wid] = inc;
  __syncthreads();
  if (tid < 16){
    int x = wsum[tid];
    #pragma unroll
    for (int d = 1; d < 16; d <<= 1){
      int t2 = __shfl_up(x, d, 16);
      if (tid >= d) x += t2;
    }
    wsum[tid] = x;
  }
  __syncthreads();
  int incl = ((wid > 0) ? wsum[wid-1] : 0) + inc;
  if (i < n) offs[i+1] = incl;
  if (tid == 0) bsum[blockIdx.x] = wsum[15];
}

// phase2: single-block exclusive scan of block sums (nb <= 1024)
__global__ __launch_bounds__(1024) void k_scan2(int* __restrict__ bsum, int nb)
{
  __shared__ int wsum[16];
  const int tid = threadIdx.x, lane = tid & 63, wid = tid >> 6;
  int v = (tid < nb) ? bsum[tid] : 0;
  int inc = v;
  #pragma unroll
  for (int d = 1; d < 64; d <<= 1){
    int t2 = __shfl_up(inc, d, 64);
    if (lane >= d) inc += t2;
  }
  if (lane == 63) wsum[wid] = inc;
  __syncthreads();
  if (tid < 16){
    int x = wsum[tid];
    #pragma unroll
    for (int d = 1; d < 16; d <<= 1){
      int t2 = __shfl_up(x, d, 16);
      if (tid >= d) x += t2;
    }
    wsum[tid] = x;
  }
  __syncthreads();
  int excl = ((wid > 0) ? wsum[wid-1] : 0) + inc - v;
  if (tid < nb) bsum[tid] = excl;
}

// phase3: add block prefix, final offs[i+1]; cursor[i]=offs[i]
__global__ void k_scan3(const int* __restrict__ cnt, const int* __restrict__ bsum,
                        int* __restrict__ offs, int* __restrict__ cursor, int n)
{
  int i = blockIdx.x * blockDim.x + threadIdx.x;
  if (i >= n) return;
  int v = offs[i+1] + bsum[i >> 10];
  offs[i+1] = v;
  cursor[i] = v - cnt[i];
  if (i == 0) offs[0] = 0;
}

// Scatter into both CSRs, folding ALL per-edge static data into the records:
//  D-CSR: recD[p] = { src, c1_const_bits, c2_const_bits, 0 }  (16B, one line)
//  U-CSR: srtOU[p] = dst                                       (4B)
__global__ __launch_bounds__(256) void k_scatter_both(
    const int* __restrict__ esrc, const int* __restrict__ edst,
    const int* __restrict__ ecat, const float* __restrict__ enum_,
    const float* __restrict__ tab1, const float* __restrict__ tab2,
    int* __restrict__ curU, int* __restrict__ curD,
    int4* __restrict__ recD, int* __restrict__ srtOU, int E)
{
  int e = blockIdx.x * blockDim.x + threadIdx.x;
  if (e >= E) return;
  int s = esrc[e], d = edst[e];
  int c0 = ecat[e*3], c1i = ecat[e*3+1], c2i = ecat[e*3+2];
  float n0 = enum_[e*3], n1 = enum_[e*3+1], n2 = enum_[e*3+2];
  float cA = tab1[c0] + tab1[20+c1i] + tab1[40+c2i]
           + n0*tab1[60] + n1*tab1[61] + n2*tab1[62] + tab1[63];
  float cB = tab2[c0] + tab2[20+c1i] + tab2[40+c2i]
           + n0*tab2[60] + n1*tab2[61] + n2*tab2[62] + tab2[63];
  int pD = atomicAdd(&curD[d], 1);
  recD[pD] = make_int4(s, __float_as_int(cA), __float_as_int(cB), 0);
  int pU = atomicAdd(&curU[s], 1);
  srtOU[pU] = d;
}

// v-direction GAT aggregate: alpha computed on the fly from records.
// alpha = leaky( gS[rec.other] + selfS[node] + rec.c{1|2} ); online softmax;
// weighted gather of xs rows; bias+ReLU; optional fused dot sout = out . qd.
__global__ __launch_bounds__(256) void k_agg_v(
    const int* __restrict__ offs, const int4* __restrict__ rec,
    const float* __restrict__ gS, const float* __restrict__ selfS, int lsel,
    const float* __restrict__ xs, const float* __restrict__ bias,
    float* __restrict__ out, const float* __restrict__ qd,
    float* __restrict__ sout, int N)
{
  int w = (blockIdx.x*blockDim.x + threadIdx.x) >> 6;
  int lane = threadIdx.x & 63;
  if (w >= N) return;
  const int beg = offs[w], end = offs[w+1];
  const float uni = selfS[w];

  float m = -1e30f, s = 0.f;
  for (int base = beg; base < end; base += 64){
    int i = base + lane;
    if (i < end){
      int4 r = rec[i];
      float a = gS[r.x] + uni + __int_as_float(lsel ? r.z : r.y);
      a = a > 0.f ? a : 0.2f * a;
      float mn = fmaxf(m, a);
      s = s*__expf(m - mn) + __expf(a - mn);
      m = mn;
    }
  }
  wave_merge_ms(m, s);
  const float inv = 1.f / (s + 1e-16f);

  float a0 = 0.f, a1 = 0.f;
  const float2* xs2 = (const float2*)xs;
  for (int base = beg; base < end; base += 64){
    int i = base + lane;
    int o = 0; float wgt = 0.f;
    if (i < end){
      int4 r = rec[i];
      o = r.x;
      float a = gS[o] + uni + __int_as_float(lsel ? r.z : r.y);
      a = a > 0.f ? a : 0.2f * a;
      wgt = __expf(a - m) * inv;
    }
    int nn = min(64, end - base);
    for (int j = 0; j < nn; ++j){
      int   oo = __shfl(o, j, 64);
      float ww = __shfl(wgt, j, 64);
      float2 v = xs2[(size_t)oo*64 + lane];
      a0 += ww * v.x; a1 += ww * v.y;
    }
  }
  float2 bb = ((const float2*)bias)[lane];
  float r0 = fmaxf(a0 + bb.x, 0.f);
  float r1 = fmaxf(a1 + bb.y, 0.f);
  ((float2*)out)[(size_t)w*64 + lane] = make_float2(r0, r1);
  if (qd){
    float2 q = ((const float2*)qd)[lane];
    float p = wave_reduce_sum(r0*q.x + r1*q.y);
    if (lane == 0) sout[w] = p;
  }
}

// r-direction: same but record is just 'other' (dst node), no edge const.
__global__ __launch_bounds__(256) void k_agg_r(
    const int* __restrict__ offs, const int* __restrict__ srtO,
    const float* __restrict__ gS, const float* __restrict__ selfS,
    const float* __restrict__ xs, const float* __restrict__ bias,
    float* __restrict__ out, const float* __restrict__ qd,
    float* __restrict__ sout, int N)
{
  int w = (blockIdx.x*blockDim.x + threadIdx.x) >> 6;
  int lane = threadIdx.x & 63;
  if (w >= N) return;
  const int beg = offs[w], end = offs[w+1];
  const float uni = selfS[w];

  float m = -1e30f, s = 0.f;
  for (int base = beg; base < end; base += 64){
    int i = base + lane;
    if (i < end){
      float a = gS[srtO[i]] + uni;
      a = a > 0.f ? a : 0.2f * a;
      float mn = fmaxf(m, a);
      s = s*__expf(m - mn) + __expf(a - mn);
      m = mn;
    }
  }
  wave_merge_ms(m, s);
  const float inv = 1.f / (s + 1e-16f);

  float a0 = 0.f, a1 = 0.f;
  const float2* xs2 = (const float2*)xs;
  for (int base = beg; base < end; base += 64){
    int i = base + lane;
    int o = 0; float wgt = 0.f;
    if (i < end){
      o = srtO[i];
      float a = gS[o] + uni;
      a = a > 0.f ? a : 0.2f * a;
      wgt = __expf(a - m) * inv;
    }
    int nn = min(64, end - base);
    for (int j = 0; j < nn; ++j){
      int   oo = __shfl(o, j, 64);
      float ww = __shfl(wgt, j, 64);
      float2 v = xs2[(size_t)oo*64 + lane];
      a0 += ww * v.x; a1 += ww * v.y;
    }
  }
  float2 bb = ((const float2*)bias)[lane];
  float r0 = fmaxf(a0 + bb.x, 0.f);
  float r1 = fmaxf(a1 + bb.y, 0.f);
  ((float2*)out)[(size_t)w*64 + lane] = make_float2(r0, r1);
  if (qd){
    float2 q = ((const float2*)qd)[lane];
    float p = wave_reduce_sum(r0*q.x + r1*q.y);
    if (lane == 0) sout[w] = p;
  }
}

// pred[l] = mu_u[label_src[l],:] . mu_d[label_dst[l],:]  (wave per label, O=64)
__global__ void k_pred(const int* __restrict__ ls, const int* __restrict__ ld,
                       const float* __restrict__ mu_u, const float* __restrict__ mu_d,
                       float* __restrict__ pred, int L)
{
  int wid  = (blockIdx.x * blockDim.x + threadIdx.x) >> 6;
  int lane = threadIdx.x & 63;
  if (wid >= L) return;
  float p = mu_u[(size_t)ls[wid]*64 + lane] * mu_d[(size_t)ld[wid]*64 + lane];
  p = wave_reduce_sum(p);
  if (lane == 0) pred[wid] = p;
}

extern "C" void kernel_launch(void* const* d_in, const int* in_sizes, int n_in,
                              void* d_out, int out_size, void* d_ws, size_t ws_size,
                              hipStream_t stream)
{
  (void)n_in; (void)out_size; (void)ws_size;
  const float* x_user    = (const float*)d_in[0];
  const float* x_dest    = (const float*)d_in[1];
  const int*   edge_src  = (const int*)d_in[2];
  const int*   edge_dst  = (const int*)d_in[3];
  const int*   eattr_cat = (const int*)d_in[4];
  const float* eattr_num = (const float*)d_in[5];
  const int*   label_src = (const int*)d_in[6];
  const int*   label_dst = (const int*)d_in[7];
  const float* user_emb  = (const float*)d_in[8];
  const float* dest_emb  = (const float*)d_in[9];
  const float* Wuf = (const float*)d_in[10]; const float* buf_ = (const float*)d_in[11];
  const float* Wdf = (const float*)d_in[12]; const float* bdf  = (const float*)d_in[13];
  const float* emb_acc    = (const float*)d_in[14];
  const float* emb_trans  = (const float*)d_in[15];
  const float* emb_season = (const float*)d_in[16];
  const float* Wnum = (const float*)d_in[17]; const float* bnum  = (const float*)d_in[18];
  const float* Weout = (const float*)d_in[19]; const float* beout = (const float*)d_in[20];
  const float* c1v_Ws = (const float*)d_in[21]; const float* c1v_Wd = (const float*)d_in[22];
  const float* c1v_as = (const float*)d_in[23]; const float* c1v_ad = (const float*)d_in[24];
  const float* c1v_We = (const float*)d_in[25]; const float* c1v_ae = (const float*)d_in[26];
  const float* c1v_b  = (const float*)d_in[27];
  const float* c1r_Ws = (const float*)d_in[28]; const float* c1r_Wd = (const float*)d_in[29];
  const float* c1r_as = (const float*)d_in[30]; const float* c1r_ad = (const float*)d_in[31];
  const float* c1r_b  = (const float*)d_in[32];
  const float* c2v_W  = (const float*)d_in[33]; const float* c2v_as = (const float*)d_in[34];
  const float* c2v_ad = (const float*)d_in[35]; const float* c2v_We = (const float*)d_in[36];
  const float* c2v_ae = (const float*)d_in[37]; const float* c2v_b  = (const float*)d_in[38];
  const float* c2r_W  = (const float*)d_in[39]; const float* c2r_as = (const float*)d_in[40];
  const float* c2r_ad = (const float*)d_in[41]; const float* c2r_b  = (const float*)d_in[42];
  const float* Wmu = (const float*)d_in[43]; const float* bmu = (const float*)d_in[44];
  const float* Wls = (const float*)d_in[45]; const float* bls = (const float*)d_in[46];

  const int U = in_sizes[0] / 3;
  const int D = in_sizes[1];
  const int E = in_sizes[2];
  const int L = in_sizes[6];
  const int O = 64;
  const int nbD = CDIV(D, 1024), nbU = CDIV(U, 1024);

  // ---- workspace layout ----
  float* fw = (float*)d_ws;
  size_t off = 0;
  auto falloc = [&](size_t n)->float*{ float* p = fw + off; off += (n + 3) & ~(size_t)3; return p; };
  float* A    = falloc((size_t)U * H);   // h_user -> hu -> zu
  float* BIG  = falloc((size_t)U * H);   // xs (v-direction payloads)
  float* Bd   = falloc((size_t)D * H);   // h_dest -> hd -> zd
  float* SM   = falloc((size_t)D * H);   // xs (r-direction payloads)
  float* sUa  = falloc(U);               // ssrc (U-indexed, v-dir)
  float* sUb  = falloc(U);               // sdst (U-indexed, r-dir)
  float* sDa  = falloc(D);               // sdst (D-indexed, v-dir)
  float* sDb  = falloc(D);               // ssrc (D-indexed, r-dir)
  float* sml  = falloc(17152);
  int* iw = (int*)(fw + off);
  size_t ioff = 0;
  auto ialloc = [&](size_t n)->int*{ int* p = iw + ioff; ioff += (n + 3) & ~(size_t)3; return p; };
  int* recD  = ialloc((size_t)E * 4);    // int4 records, 16B aligned
  int* srtOU = ialloc(E);
  int* cntD  = ialloc(D);
  int* curD  = ialloc(D);
  int* offsD = ialloc((size_t)D + 1);
  int* cntU  = ialloc(U);
  int* curU  = ialloc(U);
  int* offsU = ialloc((size_t)U + 1);
  int* bsumD = ialloc(1024);
  int* bsumU = ialloc(1024);

  float* outp = (float*)d_out;
  float* pred = outp;
  float* mu_u = outp + L;
  float* mu_d = mu_u + (size_t)U * O;
  float* ls_u = mu_d + (size_t)D * O;
  float* ls_d = ls_u + (size_t)U * O;

  // ---- precompute + encoders (fused layer-1 sdst dots) ----
  hipLaunchKernelGGL(k_precompute, dim3(12), dim3(128), 0, stream,
                     c1v_Wd, c1v_ad, c1r_Wd, c1r_ad, c2v_W, c2v_ad, c2r_W, c2r_ad,
                     c1v_We, c1v_ae, c2v_We, c2v_ae, Weout, beout,
                     emb_acc, emb_trans, emb_season, Wnum, bnum, Wmu, Wls, bmu, bls, sml);
  hipLaunchKernelGGL(k_enc_user, dim3(CDIV(U,4)), dim3(256), 0, stream,
                     user_emb, x_user, Wuf, buf_, sml+128, A, sUb, U);
  hipLaunchKernelGGL(k_enc_dest, dim3(CDIV(D,4)), dim3(256), 0, stream,
                     dest_emb, x_dest, Wdf, bdf, sml+0, Bd, sDa, D);

  // ---- CSR build (scatter folds per-edge consts for BOTH layers) ----
  hipLaunchKernelGGL(k_zero2, dim3(CDIV(U+D,256)), dim3(256), 0, stream, cntU, U, cntD, D);
  hipLaunchKernelGGL(k_count_both, dim3(CDIV(E,256)), dim3(256), 0, stream,
                     edge_src, edge_dst, cntU, cntD, E);
  hipLaunchKernelGGL(k_scan1, dim3(nbD), dim3(1024), 0, stream, cntD, offsD, bsumD, D);
  hipLaunchKernelGGL(k_scan1, dim3(nbU), dim3(1024), 0, stream, cntU, offsU, bsumU, U);
  hipLaunchKernelGGL(k_scan2, dim3(1), dim3(1024), 0, stream, bsumD, nbD);
  hipLaunchKernelGGL(k_scan2, dim3(1), dim3(1024), 0, stream, bsumU, nbU);
  hipLaunchKernelGGL(k_scan3, dim3(CDIV(D,256)), dim3(256), 0, stream, cntD, bsumD, offsD, curD, D);
  hipLaunchKernelGGL(k_scan3, dim3(CDIV(U,256)), dim3(256), 0, stream, cntU, bsumU, offsU, curU, U);
  hipLaunchKernelGGL(k_scatter_both, dim3(CDIV(E,256)), dim3(256), 0, stream,
                     edge_src, edge_dst, eattr_cat, eattr_num, sml+512, sml+576,
                     curU, curD, (int4*)recD, srtOU, E);

  // ---- layer 1 ----
  hipLaunchKernelGGL(k_gemm128, dim3(CDIV(U,64)), dim3(256), 0, stream,
                     A,  c1v_Ws, (const float*)nullptr, c1v_as, sUa, BIG, BIG+64, 128, 128, U);
  hipLaunchKernelGGL(k_gemm128, dim3(CDIV(D,64)), dim3(256), 0, stream,
                     Bd, c1r_Ws, (const float*)nullptr, c1r_as, sDb, SM, SM+64, 128, 128, D);
  hipLaunchKernelGGL(k_agg_v, dim3(CDIV(D,4)), dim3(256), 0, stream,
                     offsD, (const int4*)recD, sUa, sDa, 0, BIG, c1v_b, Bd, sml+256, sDa, D); // hd (+sdst2v)
  hipLaunchKernelGGL(k_agg_r, dim3(CDIV(U,4)), dim3(256), 0, stream,
                     offsU, srtOU, sDb, sUb, SM, c1r_b, A, sml+384, sUb, U);                  // hu (+sdst2r)

  // ---- layer 2 ----
  hipLaunchKernelGGL(k_gemm128, dim3(CDIV(U,64)), dim3(256), 0, stream,
                     A,  c2v_W, (const float*)nullptr, c2v_as, sUa, BIG, BIG+64, 128, 128, U);
  hipLaunchKernelGGL(k_gemm128, dim3(CDIV(D,64)), dim3(256), 0, stream,
                     Bd, c2r_W, (const float*)nullptr, c2r_as, sDb, SM, SM+64, 128, 128, D);
  hipLaunchKernelGGL(k_agg_v, dim3(CDIV(D,4)), dim3(256), 0, stream,
                     offsD, (const int4*)recD, sUa, sDa, 1, BIG, c2v_b, Bd,
                     (const float*)nullptr, (float*)nullptr, D);                              // zd
  hipLaunchKernelGGL(k_agg_r, dim3(CDIV(U,4)), dim3(256), 0, stream,
                     offsU, srtOU, sDb, sUb, SM, c2r_b, A,
                     (const float*)nullptr, (float*)nullptr, U);                              // zu

  // ---- heads + decode ----
  hipLaunchKernelGGL(k_gemm128, dim3(CDIV(U,64)), dim3(256), 0, stream,
                     A,  sml+768, sml+640, (const float*)nullptr, (float*)nullptr, mu_u, ls_u, 64, 64, U);
  hipLaunchKernelGGL(k_gemm128, dim3(CDIV(D,64)), dim3(256), 0, stream,
                     Bd, sml+768, sml+640, (const float*)nullptr, (float*)nullptr, mu_d, ls_d, 64, 64, D);
  hipLaunchKernelGGL(k_pred, dim3(CDIV((size_t)L*64,256)), dim3(256), 0, stream,
                     label_src, label_dst, mu_u, mu_d, pred, L);
}

// Round 6
// 867.420 us; speedup vs baseline: 1.5639x; 1.0093x over previous
//
#include <hip/hip_runtime.h>
#include <hip/hip_bf16.h>
#include <hip/hip_fp16.h>
#include <math.h>

#define H 128
#define CDIV(a,b) (((a)+(b)-1)/(b))

__device__ __forceinline__ float wave_reduce_sum(float v){
  #pragma unroll
  for (int off = 32; off > 0; off >>= 1) v += __shfl_down(v, off, 64);
  return v;
}

// merge per-lane online-softmax states (m,s) across the wave (butterfly: all lanes get result)
__device__ __forceinline__ void wave_merge_ms(float& m, float& s){
  #pragma unroll
  for (int off = 32; off > 0; off >>= 1){
    float m2 = __shfl_xor(m, off, 64);
    float s2 = __shfl_xor(s, off, 64);
    float mn = fmaxf(m, m2);
    s = s*__expf(m - mn) + s2*__expf(m2 - mn);
    m = mn;
  }
}

// ---------------------------------------------------------------------------
// sm layout (floats):
//  [0..127]    qd1v   [128..255] qd1r   [256..383] qd2v   [384..511] qd2r
//  [512..575]  layer1 edge tables: sacc[20] strans[20] sseason[20] wn[3] cb[1]
//  [576..639]  layer2 edge tables
//  [640..767]  biascat = [bmu | bls]
//  [768..17151] Wcat[128][128] = [Wmu | Wls]
// ---------------------------------------------------------------------------
__global__ __launch_bounds__(128) void k_precompute(
    const float* c1v_Wd, const float* c1v_ad,
    const float* c1r_Wd, const float* c1r_ad,
    const float* c2v_W,  const float* c2v_ad,
    const float* c2r_W,  const float* c2r_ad,
    const float* c1v_We, const float* c1v_ae,
    const float* c2v_We, const float* c2v_ae,
    const float* Weout,  const float* beout,
    const float* emb_acc, const float* emb_trans, const float* emb_season,
    const float* Wnum, const float* bnum,
    const float* Wmu, const float* Wls, const float* bmu, const float* bls,
    float* sm)
{
  const int b = blockIdx.x, t = threadIdx.x;
  if (b < 4){
    const float* M; const float* a;
    if      (b == 0){ M = c1v_Wd; a = c1v_ad; }
    else if (b == 1){ M = c1r_Wd; a = c1r_ad; }
    else if (b == 2){ M = c2v_W;  a = c2v_ad; }
    else            { M = c2r_W;  a = c2r_ad; }
    float s = 0.f;
    for (int j = 0; j < H; ++j) s += M[t*H+j] * a[j];
    sm[b*H + t] = s;
  } else if (b == 4){
    __shared__ float ws[H], vs[H];
    for (int layer = 0; layer < 2; ++layer){
      const float* We = layer ? c2v_We : c1v_We;
      const float* ae = layer ? c2v_ae : c1v_ae;
      float w = 0.f;
      for (int j = 0; j < H; ++j) w += We[t*H+j] * ae[j];
      ws[t] = w;
      __syncthreads();
      float v = 0.f;
      for (int j = 0; j < H; ++j) v += Weout[t*H+j] * ws[j];
      vs[t] = v;
      __syncthreads();
      float* tab = sm + 512 + layer*64;
      if (t < 20){
        float s1 = 0.f, s2 = 0.f, s3 = 0.f;
        for (int i = 0; i < 32; ++i){
          s1 += emb_acc   [t*32+i] * vs[i];
          s2 += emb_trans [t*32+i] * vs[32+i];
          s3 += emb_season[t*32+i] * vs[64+i];
        }
        tab[t] = s1; tab[20+t] = s2; tab[40+t] = s3;
      }
      if (t < 3){
        float s = 0.f;
        for (int i = 0; i < 32; ++i) s += Wnum[t*32+i] * vs[96+i];
        tab[60+t] = s;
      }
      if (t == 0){
        float s = 0.f;
        for (int j = 0; j < H; ++j)  s += beout[j] * ws[j];
        for (int i = 0; i < 32; ++i) s += bnum[i] * vs[96+i];
        tab[63] = s;
      }
      __syncthreads();
    }
  } else {
    float* Wcat = sm + 768;
    for (int i = (b-5)*128 + t; i < 8192; i += 7*128){
      int h = i >> 6, o = i & 63;
      Wcat[h*H + o]      = Wmu[h*64 + o];
      Wcat[h*H + 64 + o] = Wls[h*64 + o];
    }
    if (b == 5) sm[640 + t] = (t < 64) ? bmu[t] : bls[t-64];
  }
}

// wave-per-row encoders, fused sdst dot: sout[r] = h[r,:] . qd
__global__ __launch_bounds__(256) void k_enc_user(
    const float* __restrict__ emb, const float* __restrict__ x,
    const float* __restrict__ Wf, const float* __restrict__ b,
    const float* __restrict__ qd, float* __restrict__ out,
    float* __restrict__ sout, int N)
{
  int w = (blockIdx.x*blockDim.x + threadIdx.x) >> 6;
  int lane = threadIdx.x & 63;
  if (w >= N) return;
  float2 e  = ((const float2*)emb)[(size_t)w*64 + lane];
  float x0 = x[w*3], x1 = x[w*3+1], x2 = x[w*3+2];
  float2 w0 = ((const float2*)Wf)[lane];
  float2 w1 = ((const float2*)Wf)[64+lane];
  float2 w2 = ((const float2*)Wf)[128+lane];
  float2 bb = ((const float2*)b)[lane];
  float h0 = e.x + bb.x + x0*w0.x + x1*w1.x + x2*w2.x;
  float h1 = e.y + bb.y + x0*w0.y + x1*w1.y + x2*w2.y;
  ((float2*)out)[(size_t)w*64 + lane] = make_float2(h0, h1);
  float2 q = ((const float2*)qd)[lane];
  float p = wave_reduce_sum(h0*q.x + h1*q.y);
  if (lane == 0) sout[w] = p;
}

__global__ __launch_bounds__(256) void k_enc_dest(
    const float* __restrict__ emb, const float* __restrict__ x,
    const float* __restrict__ Wf, const float* __restrict__ b,
    const float* __restrict__ qd, float* __restrict__ out,
    float* __restrict__ sout, int N)
{
  int w = (blockIdx.x*blockDim.x + threadIdx.x) >> 6;
  int lane = threadIdx.x & 63;
  if (w >= N) return;
  float2 e  = ((const float2*)emb)[(size_t)w*64 + lane];
  float x0 = x[w];
  float2 w0 = ((const float2*)Wf)[lane];
  float2 bb = ((const float2*)b)[lane];
  float h0 = e.x + bb.x + x0*w0.x;
  float h1 = e.y + bb.y + x0*w0.y;
  ((float2*)out)[(size_t)w*64 + lane] = make_float2(h0, h1);
  float2 q = ((const float2*)qd)[lane];
  float p = wave_reduce_sum(h0*q.x + h1*q.y);
  if (lane == 0) sout[w] = p;
}

// C[N,128] = A[N,128] @ W[128,128] (+bias). cols 0..63 -> out0, 64..127 -> out1.
// 256 threads, 64 rows/block, 4x8 register tile. Optional fused row-dot.
__global__ __launch_bounds__(256) void k_gemm128(
    const float* __restrict__ A, const float* __restrict__ W,
    const float* __restrict__ bias, const float* __restrict__ asv,
    float* __restrict__ sout,
    float* __restrict__ out0, float* __restrict__ out1,
    int ld0, int ld1, int N)
{
  __shared__ float Ws[64][128];
  __shared__ float Xs[64][132];
  __shared__ float red[64][17];
  const int tid = threadIdx.x;
  const int rb  = blockIdx.x * 64;
  const int tc  = tid & 15, tr = tid >> 4;
  const int c0  = tc * 8;
  float C[4][8] = {};
  for (int k0 = 0; k0 < 128; k0 += 64){
    for (int i = tid; i < 2048; i += 256){            // W chunk 64x128
      int k = i >> 5, c4 = i & 31;
      *(float4*)&Ws[k][c4*4] = *(const float4*)&W[(size_t)(k0+k)*128 + c4*4];
    }
    for (int i = tid; i < 1024; i += 256){            // X chunk 64 rows x 64 k
      int r = i >> 4, kg = i & 15;
      int row = rb + r;
      float4 v = make_float4(0.f,0.f,0.f,0.f);
      if (row < N) v = *(const float4*)&A[(size_t)row*128 + k0 + kg*4];
      *(float4*)&Xs[r][kg*4] = v;
    }
    __syncthreads();
    #pragma unroll 4
    for (int k = 0; k < 64; ++k){
      float4 w0 = *(float4*)&Ws[k][c0];
      float4 w1 = *(float4*)&Ws[k][c0+4];
      #pragma unroll
      for (int i = 0; i < 4; ++i){
        float x = Xs[tr*4+i][k];
        C[i][0] += x*w0.x; C[i][1] += x*w0.y; C[i][2] += x*w0.z; C[i][3] += x*w0.w;
        C[i][4] += x*w1.x; C[i][5] += x*w1.y; C[i][6] += x*w1.z; C[i][7] += x*w1.w;
      }
    }
    __syncthreads();
  }
  float4 b0 = make_float4(0,0,0,0), b1 = make_float4(0,0,0,0);
  if (bias){ b0 = *(const float4*)&bias[c0]; b1 = *(const float4*)&bias[c0+4]; }
  float4 a0 = make_float4(0,0,0,0), a1 = make_float4(0,0,0,0);
  if (asv){ a0 = *(const float4*)&asv[c0]; a1 = *(const float4*)&asv[c0+4]; }
  #pragma unroll
  for (int i = 0; i < 4; ++i){
    int row = rb + tr*4 + i;
    float s = 0.f;
    if (row < N){
      float4 v0 = make_float4(C[i][0]+b0.x, C[i][1]+b0.y, C[i][2]+b0.z, C[i][3]+b0.w);
      float4 v1 = make_float4(C[i][4]+b1.x, C[i][5]+b1.y, C[i][6]+b1.z, C[i][7]+b1.w);
      if (c0 < 64){
        *(float4*)&out0[(size_t)row*ld0 + c0]     = v0;
        *(float4*)&out0[(size_t)row*ld0 + c0 + 4] = v1;
      } else {
        *(float4*)&out1[(size_t)row*ld1 + (c0-64)]     = v0;
        *(float4*)&out1[(size_t)row*ld1 + (c0-64) + 4] = v1;
      }
      if (asv){
        s = C[i][0]*a0.x + C[i][1]*a0.y + C[i][2]*a0.z + C[i][3]*a0.w
          + C[i][4]*a1.x + C[i][5]*a1.y + C[i][6]*a1.z + C[i][7]*a1.w;
      }
    }
    if (asv) red[tr*4+i][tc] = s;
  }
  if (asv){
    __syncthreads();
    if (tid < 64){
      int row = rb + tid;
      if (row < N){
        float t = 0.f;
        #pragma unroll
        for (int j = 0; j < 16; ++j) t += red[tid][j];
        sout[row] = t;
      }
    }
  }
}

__global__ void k_zero2(int* a, int na, int* b, int nb){
  int i = blockIdx.x * blockDim.x + threadIdx.x;
  if (i < na) a[i] = 0;
  else if (i - na < nb) b[i - na] = 0;
}

__global__ void k_count_both(const int* __restrict__ esrc, const int* __restrict__ edst,
                             int* __restrict__ cntU, int* __restrict__ cntD, int E){
  int e = blockIdx.x * blockDim.x + threadIdx.x;
  if (e < E){ atomicAdd(&cntU[esrc[e]], 1); atomicAdd(&cntD[edst[e]], 1); }
}

// 3-phase scan
__global__ __launch_bounds__(1024) void k_scan1(const int* __restrict__ cnt,
                                                int* __restrict__ offs,
                                                int* __restrict__ bsum, int n)
{
  __shared__ int wsum[16];
  const int tid = threadIdx.x, lane = tid & 63, wid = tid >> 6;
  const int i = blockIdx.x * 1024 + tid;
  int v = (i < n) ? cnt[i] : 0;
  int inc = v;
  #pragma unroll
  for (int d = 1; d < 64; d <<= 1){
    int t2 = __shfl_up(inc, d, 64);
    if (lane >= d) inc += t2;
  }
  if (lane == 63) wsum[wid] = inc;
  __syncthreads();
  if (tid < 16){
    int x = wsum[tid];
    #pragma unroll
    for (int d = 1; d < 16; d <<= 1){
      int t2 = __shfl_up(x, d, 16);
      if (tid >= d) x += t2;
    }
    wsum[tid] = x;
  }
  __syncthreads();
  int incl = ((wid > 0) ? wsum[wid-1] : 0) + inc;
  if (i < n) offs[i+1] = incl;
  if (tid == 0) bsum[blockIdx.x] = wsum[15];
}

__global__ __launch_bounds__(1024) void k_scan2(int* __restrict__ bsum, int nb)
{
  __shared__ int wsum[16];
  const int tid = threadIdx.x, lane = tid & 63, wid = tid >> 6;
  int v = (tid < nb) ? bsum[tid] : 0;
  int inc = v;
  #pragma unroll
  for (int d = 1; d < 64; d <<= 1){
    int t2 = __shfl_up(inc, d, 64);
    if (lane >= d) inc += t2;
  }
  if (lane == 63) wsum[wid] = inc;
  __syncthreads();
  if (tid < 16){
    int x = wsum[tid];
    #pragma unroll
    for (int d = 1; d < 16; d <<= 1){
      int t2 = __shfl_up(x, d, 16);
      if (tid >= d) x += t2;
    }
    wsum[tid] = x;
  }
  __syncthreads();
  int excl = ((wid > 0) ? wsum[wid-1] : 0) + inc - v;
  if (tid < nb) bsum[tid] = excl;
}

__global__ void k_scan3(const int* __restrict__ cnt, const int* __restrict__ bsum,
                        int* __restrict__ offs, int* __restrict__ cursor, int n)
{
  int i = blockIdx.x * blockDim.x + threadIdx.x;
  if (i >= n) return;
  int v = offs[i+1] + bsum[i >> 10];
  offs[i+1] = v;
  cursor[i] = v - cnt[i];
  if (i == 0) offs[0] = 0;
}

// Scatter into both CSRs. D-CSR record is 8B: {src, half2(c1_const, c2_const)}.
__global__ __launch_bounds__(256) void k_scatter_both(
    const int* __restrict__ esrc, const int* __restrict__ edst,
    const int* __restrict__ ecat, const float* __restrict__ enum_,
    const float* __restrict__ tab1, const float* __restrict__ tab2,
    int* __restrict__ curU, int* __restrict__ curD,
    int2* __restrict__ recD, int* __restrict__ srtOU, int E)
{
  int e = blockIdx.x * blockDim.x + threadIdx.x;
  if (e >= E) return;
  int s = esrc[e], d = edst[e];
  int c0 = ecat[e*3], c1i = ecat[e*3+1], c2i = ecat[e*3+2];
  float n0 = enum_[e*3], n1 = enum_[e*3+1], n2 = enum_[e*3+2];
  float cA = tab1[c0] + tab1[20+c1i] + tab1[40+c2i]
           + n0*tab1[60] + n1*tab1[61] + n2*tab1[62] + tab1[63];
  float cB = tab2[c0] + tab2[20+c1i] + tab2[40+c2i]
           + n0*tab2[60] + n1*tab2[61] + n2*tab2[62] + tab2[63];
  unsigned ua = __half_as_ushort(__float2half_rn(cA));
  unsigned ub = __half_as_ushort(__float2half_rn(cB));
  int packed = (int)((ub << 16) | ua);
  int pD = atomicAdd(&curD[d], 1);
  recD[pD] = make_int2(s, packed);
  int pU = atomicAdd(&curU[s], 1);
  srtOU[pU] = d;
}

// v-direction GAT aggregate: BLOCK per dst node (4 waves split the segment).
__global__ __launch_bounds__(256) void k_agg_v(
    const int* __restrict__ offs, const int2* __restrict__ rec,
    const float* __restrict__ gS, const float* __restrict__ selfS, int lsel,
    const float* __restrict__ xs, const float* __restrict__ bias,
    float* __restrict__ out, const float* __restrict__ qd,
    float* __restrict__ sout, int N)
{
  __shared__ float lm[4], ls_[4];
  __shared__ float2 lacc[4][64];
  const int node = blockIdx.x;
  const int tid = threadIdx.x, lane = tid & 63, wv = tid >> 6;
  const int beg = offs[node], end = offs[node+1];
  const float uni = selfS[node];

  // pass 1: online m,s — threads stride the segment
  float m = -1e30f, s = 0.f;
  for (int i = beg + tid; i < end; i += 256){
    int2 r = rec[i];
    unsigned pk = (unsigned)r.y;
    float c = __half2float(__ushort_as_half((unsigned short)(lsel ? (pk >> 16) : (pk & 0xffffu))));
    float a = gS[r.x] + uni + c;
    a = a > 0.f ? a : 0.2f * a;
    float mn = fmaxf(m, a);
    s = s*__expf(m - mn) + __expf(a - mn);
    m = mn;
  }
  wave_merge_ms(m, s);
  if (lane == 0){ lm[wv] = m; ls_[wv] = s; }
  __syncthreads();
  float M = fmaxf(fmaxf(lm[0], lm[1]), fmaxf(lm[2], lm[3]));
  float S = ls_[0]*__expf(lm[0]-M) + ls_[1]*__expf(lm[1]-M)
          + ls_[2]*__expf(lm[2]-M) + ls_[3]*__expf(lm[3]-M);
  const float inv = 1.f / (S + 1e-16f);

  // pass 2: waves take contiguous quarters of the segment
  const int tot = end - beg;
  const int q = (tot + 3) >> 2;
  const int wbeg = beg + wv*q;
  const int wend = min(end, wbeg + q);
  float a0 = 0.f, a1 = 0.f;
  const float2* xs2 = (const float2*)xs;
  for (int base = wbeg; base < wend; base += 64){
    int i = base + lane;
    int o = 0; float wgt = 0.f;
    if (i < wend){
      int2 r = rec[i];
      o = r.x;
      unsigned pk = (unsigned)r.y;
      float c = __half2float(__ushort_as_half((unsigned short)(lsel ? (pk >> 16) : (pk & 0xffffu))));
      float a = gS[o] + uni + c;
      a = a > 0.f ? a : 0.2f * a;
      wgt = __expf(a - M) * inv;
    }
    int nn = min(64, wend - base);
    for (int j = 0; j < nn; ++j){
      int   oo = __shfl(o, j, 64);
      float ww = __shfl(wgt, j, 64);
      float2 v = xs2[(oo << 6) + lane];      // 32-bit offset
      a0 += ww * v.x; a1 += ww * v.y;
    }
  }
  lacc[wv][lane] = make_float2(a0, a1);
  __syncthreads();
  if (wv == 0){
    float2 t0 = lacc[0][lane], t1 = lacc[1][lane], t2 = lacc[2][lane], t3 = lacc[3][lane];
    float2 bb = ((const float2*)bias)[lane];
    float r0 = fmaxf(t0.x+t1.x+t2.x+t3.x + bb.x, 0.f);
    float r1 = fmaxf(t0.y+t1.y+t2.y+t3.y + bb.y, 0.f);
    ((float2*)out)[(size_t)node*64 + lane] = make_float2(r0, r1);
    if (qd){
      float2 qv = ((const float2*)qd)[lane];
      float p = wave_reduce_sum(r0*qv.x + r1*qv.y);
      if (lane == 0) sout[node] = p;
    }
  }
}

// r-direction: wave per node; record is just 'other'. 32-bit offsets.
__global__ __launch_bounds__(256) void k_agg_r(
    const int* __restrict__ offs, const int* __restrict__ srtO,
    const float* __restrict__ gS, const float* __restrict__ selfS,
    const float* __restrict__ xs, const float* __restrict__ bias,
    float* __restrict__ out, const float* __restrict__ qd,
    float* __restrict__ sout, int N)
{
  int w = (blockIdx.x*blockDim.x + threadIdx.x) >> 6;
  int lane = threadIdx.x & 63;
  if (w >= N) return;
  const int beg = offs[w], end = offs[w+1];
  const float uni = selfS[w];

  float m = -1e30f, s = 0.f;
  for (int i = beg + lane; i < end; i += 64){
    float a = gS[srtO[i]] + uni;
    a = a > 0.f ? a : 0.2f * a;
    float mn = fmaxf(m, a);
    s = s*__expf(m - mn) + __expf(a - mn);
    m = mn;
  }
  wave_merge_ms(m, s);
  const float inv = 1.f / (s + 1e-16f);

  float a0 = 0.f, a1 = 0.f;
  const float2* xs2 = (const float2*)xs;
  for (int base = beg; base < end; base += 64){
    int i = base + lane;
    int o = 0; float wgt = 0.f;
    if (i < end){
      o = srtO[i];
      float a = gS[o] + uni;
      a = a > 0.f ? a : 0.2f * a;
      wgt = __expf(a - m) * inv;
    }
    int nn = min(64, end - base);
    for (int j = 0; j < nn; ++j){
      int   oo = __shfl(o, j, 64);
      float ww = __shfl(wgt, j, 64);
      float2 v = xs2[(oo << 6) + lane];      // 32-bit offset
      a0 += ww * v.x; a1 += ww * v.y;
    }
  }
  float2 bb = ((const float2*)bias)[lane];
  float r0 = fmaxf(a0 + bb.x, 0.f);
  float r1 = fmaxf(a1 + bb.y, 0.f);
  ((float2*)out)[(size_t)w*64 + lane] = make_float2(r0, r1);
  if (qd){
    float2 q = ((const float2*)qd)[lane];
    float p = wave_reduce_sum(r0*q.x + r1*q.y);
    if (lane == 0) sout[w] = p;
  }
}

// pred[l] = mu_u[label_src[l],:] . mu_d[label_dst[l],:]  (wave per label, O=64)
__global__ void k_pred(const int* __restrict__ ls, const int* __restrict__ ld,
                       const float* __restrict__ mu_u, const float* __restrict__ mu_d,
                       float* __restrict__ pred, int L)
{
  int wid  = (blockIdx.x * blockDim.x + threadIdx.x) >> 6;
  int lane = threadIdx.x & 63;
  if (wid >= L) return;
  float p = mu_u[(ls[wid] << 6) + lane] * mu_d[(ld[wid] << 6) + lane];
  p = wave_reduce_sum(p);
  if (lane == 0) pred[wid] = p;
}

extern "C" void kernel_launch(void* const* d_in, const int* in_sizes, int n_in,
                              void* d_out, int out_size, void* d_ws, size_t ws_size,
                              hipStream_t stream)
{
  (void)n_in; (void)out_size; (void)ws_size;
  const float* x_user    = (const float*)d_in[0];
  const float* x_dest    = (const float*)d_in[1];
  const int*   edge_src  = (const int*)d_in[2];
  const int*   edge_dst  = (const int*)d_in[3];
  const int*   eattr_cat = (const int*)d_in[4];
  const float* eattr_num = (const float*)d_in[5];
  const int*   label_src = (const int*)d_in[6];
  const int*   label_dst = (const int*)d_in[7];
  const float* user_emb  = (const float*)d_in[8];
  const float* dest_emb  = (const float*)d_in[9];
  const float* Wuf = (const float*)d_in[10]; const float* buf_ = (const float*)d_in[11];
  const float* Wdf = (const float*)d_in[12]; const float* bdf  = (const float*)d_in[13];
  const float* emb_acc    = (const float*)d_in[14];
  const float* emb_trans  = (const float*)d_in[15];
  const float* emb_season = (const float*)d_in[16];
  const float* Wnum = (const float*)d_in[17]; const float* bnum  = (const float*)d_in[18];
  const float* Weout = (const float*)d_in[19]; const float* beout = (const float*)d_in[20];
  const float* c1v_Ws = (const float*)d_in[21]; const float* c1v_Wd = (const float*)d_in[22];
  const float* c1v_as = (const float*)d_in[23]; const float* c1v_ad = (const float*)d_in[24];
  const float* c1v_We = (const float*)d_in[25]; const float* c1v_ae = (const float*)d_in[26];
  const float* c1v_b  = (const float*)d_in[27];
  const float* c1r_Ws = (const float*)d_in[28]; const float* c1r_Wd = (const float*)d_in[29];
  const float* c1r_as = (const float*)d_in[30]; const float* c1r_ad = (const float*)d_in[31];
  const float* c1r_b  = (const float*)d_in[32];
  const float* c2v_W  = (const float*)d_in[33]; const float* c2v_as = (const float*)d_in[34];
  const float* c2v_ad = (const float*)d_in[35]; const float* c2v_We = (const float*)d_in[36];
  const float* c2v_ae = (const float*)d_in[37]; const float* c2v_b  = (const float*)d_in[38];
  const float* c2r_W  = (const float*)d_in[39]; const float* c2r_as = (const float*)d_in[40];
  const float* c2r_ad = (const float*)d_in[41]; const float* c2r_b  = (const float*)d_in[42];
  const float* Wmu = (const float*)d_in[43]; const float* bmu = (const float*)d_in[44];
  const float* Wls = (const float*)d_in[45]; const float* bls = (const float*)d_in[46];

  const int U = in_sizes[0] / 3;
  const int D = in_sizes[1];
  const int E = in_sizes[2];
  const int L = in_sizes[6];
  const int O = 64;
  const int nbD = CDIV(D, 1024), nbU = CDIV(U, 1024);

  // ---- workspace layout ----
  float* fw = (float*)d_ws;
  size_t off = 0;
  auto falloc = [&](size_t n)->float*{ float* p = fw + off; off += (n + 3) & ~(size_t)3; return p; };
  float* A    = falloc((size_t)U * H);   // h_user -> hu -> zu
  float* BIG  = falloc((size_t)U * H);   // xs (v-direction payloads)
  float* Bd   = falloc((size_t)D * H);   // h_dest -> hd -> zd
  float* SM   = falloc((size_t)D * H);   // xs (r-direction payloads)
  float* sUa  = falloc(U);               // ssrc (U-indexed, v-dir)
  float* sUb  = falloc(U);               // sdst (U-indexed, r-dir)
  float* sDa  = falloc(D);               // sdst (D-indexed, v-dir)
  float* sDb  = falloc(D);               // ssrc (D-indexed, r-dir)
  float* sml  = falloc(17152);
  int* iw = (int*)(fw + off);
  size_t ioff = 0;
  auto ialloc = [&](size_t n)->int*{ int* p = iw + ioff; ioff += (n + 3) & ~(size_t)3; return p; };
  int* recD  = ialloc((size_t)E * 2);    // int2 records (8B)
  int* srtOU = ialloc(E);
  int* cntD  = ialloc(D);
  int* curD  = ialloc(D);
  int* offsD = ialloc((size_t)D + 1);
  int* cntU  = ialloc(U);
  int* curU  = ialloc(U);
  int* offsU = ialloc((size_t)U + 1);
  int* bsumD = ialloc(1024);
  int* bsumU = ialloc(1024);

  float* outp = (float*)d_out;
  float* pred = outp;
  float* mu_u = outp + L;
  float* mu_d = mu_u + (size_t)U * O;
  float* ls_u = mu_d + (size_t)D * O;
  float* ls_d = ls_u + (size_t)U * O;

  // ---- precompute + encoders (fused layer-1 sdst dots) ----
  hipLaunchKernelGGL(k_precompute, dim3(12), dim3(128), 0, stream,
                     c1v_Wd, c1v_ad, c1r_Wd, c1r_ad, c2v_W, c2v_ad, c2r_W, c2r_ad,
                     c1v_We, c1v_ae, c2v_We, c2v_ae, Weout, beout,
                     emb_acc, emb_trans, emb_season, Wnum, bnum, Wmu, Wls, bmu, bls, sml);
  hipLaunchKernelGGL(k_enc_user, dim3(CDIV(U,4)), dim3(256), 0, stream,
                     user_emb, x_user, Wuf, buf_, sml+128, A, sUb, U);
  hipLaunchKernelGGL(k_enc_dest, dim3(CDIV(D,4)), dim3(256), 0, stream,
                     dest_emb, x_dest, Wdf, bdf, sml+0, Bd, sDa, D);

  // ---- CSR build ----
  hipLaunchKernelGGL(k_zero2, dim3(CDIV(U+D,256)), dim3(256), 0, stream, cntU, U, cntD, D);
  hipLaunchKernelGGL(k_count_both, dim3(CDIV(E,256)), dim3(256), 0, stream,
                     edge_src, edge_dst, cntU, cntD, E);
  hipLaunchKernelGGL(k_scan1, dim3(nbD), dim3(1024), 0, stream, cntD, offsD, bsumD, D);
  hipLaunchKernelGGL(k_scan1, dim3(nbU), dim3(1024), 0, stream, cntU, offsU, bsumU, U);
  hipLaunchKernelGGL(k_scan2, dim3(1), dim3(1024), 0, stream, bsumD, nbD);
  hipLaunchKernelGGL(k_scan2, dim3(1), dim3(1024), 0, stream, bsumU, nbU);
  hipLaunchKernelGGL(k_scan3, dim3(CDIV(D,256)), dim3(256), 0, stream, cntD, bsumD, offsD, curD, D);
  hipLaunchKernelGGL(k_scan3, dim3(CDIV(U,256)), dim3(256), 0, stream, cntU, bsumU, offsU, curU, U);
  hipLaunchKernelGGL(k_scatter_both, dim3(CDIV(E,256)), dim3(256), 0, stream,
                     edge_src, edge_dst, eattr_cat, eattr_num, sml+512, sml+576,
                     curU, curD, (int2*)recD, srtOU, E);

  // ---- layer 1 ----
  hipLaunchKernelGGL(k_gemm128, dim3(CDIV(U,64)), dim3(256), 0, stream,
                     A,  c1v_Ws, (const float*)nullptr, c1v_as, sUa, BIG, BIG+64, 128, 128, U);
  hipLaunchKernelGGL(k_gemm128, dim3(CDIV(D,64)), dim3(256), 0, stream,
                     Bd, c1r_Ws, (const float*)nullptr, c1r_as, sDb, SM, SM+64, 128, 128, D);
  hipLaunchKernelGGL(k_agg_v, dim3(D), dim3(256), 0, stream,
                     offsD, (const int2*)recD, sUa, sDa, 0, BIG, c1v_b, Bd, sml+256, sDa, D); // hd (+sdst2v)
  hipLaunchKernelGGL(k_agg_r, dim3(CDIV(U,4)), dim3(256), 0, stream,
                     offsU, srtOU, sDb, sUb, SM, c1r_b, A, sml+384, sUb, U);                  // hu (+sdst2r)

  // ---- layer 2 ----
  hipLaunchKernelGGL(k_gemm128, dim3(CDIV(U,64)), dim3(256), 0, stream,
                     A,  c2v_W, (const float*)nullptr, c2v_as, sUa, BIG, BIG+64, 128, 128, U);
  hipLaunchKernelGGL(k_gemm128, dim3(CDIV(D,64)), dim3(256), 0, stream,
                     Bd, c2r_W, (const float*)nullptr, c2r_as, sDb, SM, SM+64, 128, 128, D);
  hipLaunchKernelGGL(k_agg_v, dim3(D), dim3(256), 0, stream,
                     offsD, (const int2*)recD, sUa, sDa, 1, BIG, c2v_b, Bd,
                     (const float*)nullptr, (float*)nullptr, D);                              // zd
  hipLaunchKernelGGL(k_agg_r, dim3(CDIV(U,4)), dim3(256), 0, stream,
                     offsU, srtOU, sDb, sUb, SM, c2r_b, A,
                     (const float*)nullptr, (float*)nullptr, U);                              // zu

  // ---- heads + decode ----
  hipLaunchKernelGGL(k_gemm128, dim3(CDIV(U,64)), dim3(256), 0, stream,
                     A,  sml+768, sml+640, (const float*)nullptr, (float*)nullptr, mu_u, ls_u, 64, 64, U);
  hipLaunchKernelGGL(k_gemm128, dim3(CDIV(D,64)), dim3(256), 0, stream,
                     Bd, sml+768, sml+640, (const float*)nullptr, (float*)nullptr, mu_d, ls_d, 64, 64, D);
  hipLaunchKernelGGL(k_pred, dim3(CDIV((size_t)L*64,256)), dim3(256), 0, stream,
                     label_src, label_dst, mu_u, mu_d, pred, L);
}

// Round 7
// 792.439 us; speedup vs baseline: 1.7119x; 1.0946x over previous
//
#include <hip/hip_runtime.h>
#include <hip/hip_bf16.h>
#include <hip/hip_fp16.h>
#include <math.h>

#define H 128
#define CDIV(a,b) (((a)+(b)-1)/(b))

__device__ __forceinline__ float wave_reduce_sum(float v){
  #pragma unroll
  for (int off = 32; off > 0; off >>= 1) v += __shfl_down(v, off, 64);
  return v;
}

__device__ __forceinline__ float unpack_c(int pk, int lsel){
  unsigned u = (unsigned)pk;
  unsigned short h = (unsigned short)(lsel ? (u >> 16) : (u & 0xffffu));
  return __half2float(__ushort_as_half(h));
}

// ---------------------------------------------------------------------------
// sm layout (floats):
//  [0..127]    qd1v   [128..255] qd1r   [256..383] qd2v   [384..511] qd2r
//  [512..575]  layer1 edge tables: sacc[20] strans[20] sseason[20] wn[3] cb[1]
//  [576..639]  layer2 edge tables
//  [640..767]  biascat = [bmu | bls]
//  [768..17151] Wcat[128][128] = [Wmu | Wls]
// ---------------------------------------------------------------------------
__global__ __launch_bounds__(128) void k_precompute(
    const float* c1v_Wd, const float* c1v_ad,
    const float* c1r_Wd, const float* c1r_ad,
    const float* c2v_W,  const float* c2v_ad,
    const float* c2r_W,  const float* c2r_ad,
    const float* c1v_We, const float* c1v_ae,
    const float* c2v_We, const float* c2v_ae,
    const float* Weout,  const float* beout,
    const float* emb_acc, const float* emb_trans, const float* emb_season,
    const float* Wnum, const float* bnum,
    const float* Wmu, const float* Wls, const float* bmu, const float* bls,
    float* sm)
{
  const int b = blockIdx.x, t = threadIdx.x;
  if (b < 4){
    const float* M; const float* a;
    if      (b == 0){ M = c1v_Wd; a = c1v_ad; }
    else if (b == 1){ M = c1r_Wd; a = c1r_ad; }
    else if (b == 2){ M = c2v_W;  a = c2v_ad; }
    else            { M = c2r_W;  a = c2r_ad; }
    float s = 0.f;
    for (int j = 0; j < H; ++j) s += M[t*H+j] * a[j];
    sm[b*H + t] = s;
  } else if (b == 4){
    __shared__ float ws[H], vs[H];
    for (int layer = 0; layer < 2; ++layer){
      const float* We = layer ? c2v_We : c1v_We;
      const float* ae = layer ? c2v_ae : c1v_ae;
      float w = 0.f;
      for (int j = 0; j < H; ++j) w += We[t*H+j] * ae[j];
      ws[t] = w;
      __syncthreads();
      float v = 0.f;
      for (int j = 0; j < H; ++j) v += Weout[t*H+j] * ws[j];
      vs[t] = v;
      __syncthreads();
      float* tab = sm + 512 + layer*64;
      if (t < 20){
        float s1 = 0.f, s2 = 0.f, s3 = 0.f;
        for (int i = 0; i < 32; ++i){
          s1 += emb_acc   [t*32+i] * vs[i];
          s2 += emb_trans [t*32+i] * vs[32+i];
          s3 += emb_season[t*32+i] * vs[64+i];
        }
        tab[t] = s1; tab[20+t] = s2; tab[40+t] = s3;
      }
      if (t < 3){
        float s = 0.f;
        for (int i = 0; i < 32; ++i) s += Wnum[t*32+i] * vs[96+i];
        tab[60+t] = s;
      }
      if (t == 0){
        float s = 0.f;
        for (int j = 0; j < H; ++j)  s += beout[j] * ws[j];
        for (int i = 0; i < 32; ++i) s += bnum[i] * vs[96+i];
        tab[63] = s;
      }
      __syncthreads();
    }
  } else {
    float* Wcat = sm + 768;
    for (int i = (b-5)*128 + t; i < 8192; i += 7*128){
      int h = i >> 6, o = i & 63;
      Wcat[h*H + o]      = Wmu[h*64 + o];
      Wcat[h*H + 64 + o] = Wls[h*64 + o];
    }
    if (b == 5) sm[640 + t] = (t < 64) ? bmu[t] : bls[t-64];
  }
}

// wave-per-row encoders, fused sdst dot: sout[r] = h[r,:] . qd
__global__ __launch_bounds__(256) void k_enc_user(
    const float* __restrict__ emb, const float* __restrict__ x,
    const float* __restrict__ Wf, const float* __restrict__ b,
    const float* __restrict__ qd, float* __restrict__ out,
    float* __restrict__ sout, int N)
{
  int w = (blockIdx.x*blockDim.x + threadIdx.x) >> 6;
  int lane = threadIdx.x & 63;
  if (w >= N) return;
  float2 e  = ((const float2*)emb)[(size_t)w*64 + lane];
  float x0 = x[w*3], x1 = x[w*3+1], x2 = x[w*3+2];
  float2 w0 = ((const float2*)Wf)[lane];
  float2 w1 = ((const float2*)Wf)[64+lane];
  float2 w2 = ((const float2*)Wf)[128+lane];
  float2 bb = ((const float2*)b)[lane];
  float h0 = e.x + bb.x + x0*w0.x + x1*w1.x + x2*w2.x;
  float h1 = e.y + bb.y + x0*w0.y + x1*w1.y + x2*w2.y;
  ((float2*)out)[(size_t)w*64 + lane] = make_float2(h0, h1);
  float2 q = ((const float2*)qd)[lane];
  float p = wave_reduce_sum(h0*q.x + h1*q.y);
  if (lane == 0) sout[w] = p;
}

__global__ __launch_bounds__(256) void k_enc_dest(
    const float* __restrict__ emb, const float* __restrict__ x,
    const float* __restrict__ Wf, const float* __restrict__ b,
    const float* __restrict__ qd, float* __restrict__ out,
    float* __restrict__ sout, int N)
{
  int w = (blockIdx.x*blockDim.x + threadIdx.x) >> 6;
  int lane = threadIdx.x & 63;
  if (w >= N) return;
  float2 e  = ((const float2*)emb)[(size_t)w*64 + lane];
  float x0 = x[w];
  float2 w0 = ((const float2*)Wf)[lane];
  float2 bb = ((const float2*)b)[lane];
  float h0 = e.x + bb.x + x0*w0.x;
  float h1 = e.y + bb.y + x0*w0.y;
  ((float2*)out)[(size_t)w*64 + lane] = make_float2(h0, h1);
  float2 q = ((const float2*)qd)[lane];
  float p = wave_reduce_sum(h0*q.x + h1*q.y);
  if (lane == 0) sout[w] = p;
}

// C[N,128] = A[N,128] @ W[128,128] (+bias). cols 0..63 -> out0, 64..127 -> out1.
__global__ __launch_bounds__(256) void k_gemm128(
    const float* __restrict__ A, const float* __restrict__ W,
    const float* __restrict__ bias, const float* __restrict__ asv,
    float* __restrict__ sout,
    float* __restrict__ out0, float* __restrict__ out1,
    int ld0, int ld1, int N)
{
  __shared__ float Ws[64][128];
  __shared__ float Xs[64][132];
  __shared__ float red[64][17];
  const int tid = threadIdx.x;
  const int rb  = blockIdx.x * 64;
  const int tc  = tid & 15, tr = tid >> 4;
  const int c0  = tc * 8;
  float C[4][8] = {};
  for (int k0 = 0; k0 < 128; k0 += 64){
    for (int i = tid; i < 2048; i += 256){
      int k = i >> 5, c4 = i & 31;
      *(float4*)&Ws[k][c4*4] = *(const float4*)&W[(size_t)(k0+k)*128 + c4*4];
    }
    for (int i = tid; i < 1024; i += 256){
      int r = i >> 4, kg = i & 15;
      int row = rb + r;
      float4 v = make_float4(0.f,0.f,0.f,0.f);
      if (row < N) v = *(const float4*)&A[(size_t)row*128 + k0 + kg*4];
      *(float4*)&Xs[r][kg*4] = v;
    }
    __syncthreads();
    #pragma unroll 4
    for (int k = 0; k < 64; ++k){
      float4 w0 = *(float4*)&Ws[k][c0];
      float4 w1 = *(float4*)&Ws[k][c0+4];
      #pragma unroll
      for (int i = 0; i < 4; ++i){
        float x = Xs[tr*4+i][k];
        C[i][0] += x*w0.x; C[i][1] += x*w0.y; C[i][2] += x*w0.z; C[i][3] += x*w0.w;
        C[i][4] += x*w1.x; C[i][5] += x*w1.y; C[i][6] += x*w1.z; C[i][7] += x*w1.w;
      }
    }
    __syncthreads();
  }
  float4 b0 = make_float4(0,0,0,0), b1 = make_float4(0,0,0,0);
  if (bias){ b0 = *(const float4*)&bias[c0]; b1 = *(const float4*)&bias[c0+4]; }
  float4 a0 = make_float4(0,0,0,0), a1 = make_float4(0,0,0,0);
  if (asv){ a0 = *(const float4*)&asv[c0]; a1 = *(const float4*)&asv[c0+4]; }
  #pragma unroll
  for (int i = 0; i < 4; ++i){
    int row = rb + tr*4 + i;
    float s = 0.f;
    if (row < N){
      float4 v0 = make_float4(C[i][0]+b0.x, C[i][1]+b0.y, C[i][2]+b0.z, C[i][3]+b0.w);
      float4 v1 = make_float4(C[i][4]+b1.x, C[i][5]+b1.y, C[i][6]+b1.z, C[i][7]+b1.w);
      if (c0 < 64){
        *(float4*)&out0[(size_t)row*ld0 + c0]     = v0;
        *(float4*)&out0[(size_t)row*ld0 + c0 + 4] = v1;
      } else {
        *(float4*)&out1[(size_t)row*ld1 + (c0-64)]     = v0;
        *(float4*)&out1[(size_t)row*ld1 + (c0-64) + 4] = v1;
      }
      if (asv){
        s = C[i][0]*a0.x + C[i][1]*a0.y + C[i][2]*a0.z + C[i][3]*a0.w
          + C[i][4]*a1.x + C[i][5]*a1.y + C[i][6]*a1.z + C[i][7]*a1.w;
      }
    }
    if (asv) red[tr*4+i][tc] = s;
  }
  if (asv){
    __syncthreads();
    if (tid < 64){
      int row = rb + tid;
      if (row < N){
        float t = 0.f;
        #pragma unroll
        for (int j = 0; j < 16; ++j) t += red[tid][j];
        sout[row] = t;
      }
    }
  }
}

__global__ void k_zero2(int* a, int na, int* b, int nb){
  int i = blockIdx.x * blockDim.x + threadIdx.x;
  if (i < na) a[i] = 0;
  else if (i - na < nb) b[i - na] = 0;
}

// count both degrees + pack per-edge consts for both layers into 4B
__global__ __launch_bounds__(256) void k_pack_count(
    const int* __restrict__ esrc, const int* __restrict__ edst,
    const int* __restrict__ ecat, const float* __restrict__ enum_,
    const float* __restrict__ tab1, const float* __restrict__ tab2,
    int* __restrict__ cntU, int* __restrict__ cntD,
    int* __restrict__ packed, int E)
{
  int e = blockIdx.x * blockDim.x + threadIdx.x;
  if (e >= E) return;
  int c0 = ecat[e*3], c1i = ecat[e*3+1], c2i = ecat[e*3+2];
  float n0 = enum_[e*3], n1 = enum_[e*3+1], n2 = enum_[e*3+2];
  float cA = tab1[c0] + tab1[20+c1i] + tab1[40+c2i]
           + n0*tab1[60] + n1*tab1[61] + n2*tab1[62] + tab1[63];
  float cB = tab2[c0] + tab2[20+c1i] + tab2[40+c2i]
           + n0*tab2[60] + n1*tab2[61] + n2*tab2[62] + tab2[63];
  unsigned ua = __half_as_ushort(__float2half_rn(cA));
  unsigned ub = __half_as_ushort(__float2half_rn(cB));
  packed[e] = (int)((ub << 16) | ua);
  atomicAdd(&cntU[esrc[e]], 1);
  atomicAdd(&cntD[edst[e]], 1);
}

// 3-phase scan
__global__ __launch_bounds__(1024) void k_scan1(const int* __restrict__ cnt,
                                                int* __restrict__ offs,
                                                int* __restrict__ bsum, int n)
{
  __shared__ int wsum[16];
  const int tid = threadIdx.x, lane = tid & 63, wid = tid >> 6;
  const int i = blockIdx.x * 1024 + tid;
  int v = (i < n) ? cnt[i] : 0;
  int inc = v;
  #pragma unroll
  for (int d = 1; d < 64; d <<= 1){
    int t2 = __shfl_up(inc, d, 64);
    if (lane >= d) inc += t2;
  }
  if (lane == 63) wsum[wid] = inc;
  __syncthreads();
  if (tid < 16){
    int x = wsum[tid];
    #pragma unroll
    for (int d = 1; d < 16; d <<= 1){
      int t2 = __shfl_up(x, d, 16);
      if (tid >= d) x += t2;
    }
    wsum[tid] = x;
  }
  __syncthreads();
  int incl = ((wid > 0) ? wsum[wid-1] : 0) + inc;
  if (i < n) offs[i+1] = incl;
  if (tid == 0) bsum[blockIdx.x] = wsum[15];
}

__global__ __launch_bounds__(1024) void k_scan2(int* __restrict__ bsum, int nb)
{
  __shared__ int wsum[16];
  const int tid = threadIdx.x, lane = tid & 63, wid = tid >> 6;
  int v = (tid < nb) ? bsum[tid] : 0;
  int inc = v;
  #pragma unroll
  for (int d = 1; d < 64; d <<= 1){
    int t2 = __shfl_up(inc, d, 64);
    if (lane >= d) inc += t2;
  }
  if (lane == 63) wsum[wid] = inc;
  __syncthreads();
  if (tid < 16){
    int x = wsum[tid];
    #pragma unroll
    for (int d = 1; d < 16; d <<= 1){
      int t2 = __shfl_up(x, d, 16);
      if (tid >= d) x += t2;
    }
    wsum[tid] = x;
  }
  __syncthreads();
  int excl = ((wid > 0) ? wsum[wid-1] : 0) + inc - v;
  if (tid < nb) bsum[tid] = excl;
}

__global__ void k_scan3(const int* __restrict__ cnt, const int* __restrict__ bsum,
                        int* __restrict__ offs, int* __restrict__ cursor, int n)
{
  int i = blockIdx.x * blockDim.x + threadIdx.x;
  if (i >= n) return;
  int v = offs[i+1] + bsum[i >> 10];
  offs[i+1] = v;
  cursor[i] = v - cnt[i];
  if (i == 0) offs[0] = 0;
}

// XCD-binned scatter: block group (blockIdx&7) owns 1/8 of the dst range for
// recD writes and 1/8 of the src range for srtOU writes. Under round-robin
// dispatch the group maps to one XCD, so each slice's lines coalesce in that
// XCD's L2 (perf heuristic only; correctness is mapping-independent).
__global__ __launch_bounds__(256) void k_scatter_binned(
    const int* __restrict__ esrc, const int* __restrict__ edst,
    const int* __restrict__ packed,
    int* __restrict__ curU, int* __restrict__ curD,
    int2* __restrict__ recD, int* __restrict__ srtOU, int E, int U, int D)
{
  const int grp = blockIdx.x & 7;
  const int lb  = blockIdx.x >> 3;
  const int GB  = gridDim.x >> 3;
  const int D8 = CDIV(D, 8), U8 = CDIV(U, 8);
  const int dlo = grp * D8, dhi = min(D, dlo + D8);
  const int slo = grp * U8, shi = min(U, slo + U8);
  for (int e = lb*256 + threadIdx.x; e < E; e += GB*256){
    int s = esrc[e], d = edst[e];
    if (d >= dlo && d < dhi){
      int p = atomicAdd(&curD[d], 1);
      recD[p] = make_int2(s, packed[e]);
    }
    if (s >= slo && s < shi){
      int p = atomicAdd(&curU[s], 1);
      srtOU[p] = d;
    }
  }
}

// v-direction GAT aggregate: 32 lanes per node, 2 nodes per wave.
// alpha = leaky(gS[rec.x] + selfS[node] + rec.c); online softmax per group;
// float4 full-row gather (one load step per edge per group).
__global__ __launch_bounds__(256) void k_agg_v(
    const int* __restrict__ offs, const int2* __restrict__ rec,
    const float* __restrict__ gS, const float* __restrict__ selfS, int lsel,
    const float* __restrict__ xs, const float* __restrict__ bias,
    float* __restrict__ out, const float* __restrict__ qd,
    float* __restrict__ sout, int N)
{
  const int wid = (blockIdx.x*blockDim.x + threadIdx.x) >> 6;
  const int lane = threadIdx.x & 63;
  const int gl = lane & 31;
  const int node = wid*2 + (lane >> 5);
  if (node >= N) return;
  const int beg = offs[node], end = offs[node+1];
  const float uni = selfS[node];

  float m = -1e30f, s = 0.f;
  for (int i = beg + gl; i < end; i += 32){
    int2 r = rec[i];
    float a = gS[r.x] + uni + unpack_c(r.y, lsel);
    a = a > 0.f ? a : 0.2f * a;
    float mn = fmaxf(m, a);
    s = s*__expf(m - mn) + __expf(a - mn);
    m = mn;
  }
  #pragma unroll
  for (int off = 16; off > 0; off >>= 1){       // width-32 merge (stays in group)
    float m2 = __shfl_xor(m, off, 64);
    float s2 = __shfl_xor(s, off, 64);
    float mn = fmaxf(m, m2);
    s = s*__expf(m - mn) + s2*__expf(m2 - mn);
    m = mn;
  }
  const float inv = 1.f / (s + 1e-16f);

  float4 acc = make_float4(0.f,0.f,0.f,0.f);
  const float4* xs4 = (const float4*)xs;
  const int gbase = lane & 32;
  for (int base = beg; base < end; base += 32){
    int i = base + gl;
    int o = 0; float wgt = 0.f;
    if (i < end){
      int2 r = rec[i];
      o = r.x;
      float a = gS[o] + uni + unpack_c(r.y, lsel);
      a = a > 0.f ? a : 0.2f * a;
      wgt = __expf(a - m) * inv;
    }
    int nn = min(32, end - base);
    for (int j = 0; j < nn; ++j){
      int   oo = __shfl(o,   gbase + j, 64);
      float ww = __shfl(wgt, gbase + j, 64);
      float4 v = xs4[(oo << 5) + gl];
      acc.x += ww*v.x; acc.y += ww*v.y; acc.z += ww*v.z; acc.w += ww*v.w;
    }
  }
  float4 bb = ((const float4*)bias)[gl];
  float4 r4 = make_float4(fmaxf(acc.x+bb.x,0.f), fmaxf(acc.y+bb.y,0.f),
                          fmaxf(acc.z+bb.z,0.f), fmaxf(acc.w+bb.w,0.f));
  ((float4*)out)[(node << 5) + gl] = r4;
  if (qd){
    float4 q4 = ((const float4*)qd)[gl];
    float p = r4.x*q4.x + r4.y*q4.y + r4.z*q4.z + r4.w*q4.w;
    #pragma unroll
    for (int off = 16; off > 0; off >>= 1) p += __shfl_xor(p, off, 64);
    if (gl == 0) sout[node] = p;
  }
}

// r-direction: 16 lanes per node, 4 nodes per wave (4 independent chains/wave).
__global__ __launch_bounds__(256) void k_agg_r(
    const int* __restrict__ offs, const int* __restrict__ srtO,
    const float* __restrict__ gS, const float* __restrict__ selfS,
    const float* __restrict__ xs, const float* __restrict__ bias,
    float* __restrict__ out, const float* __restrict__ qd,
    float* __restrict__ sout, int N)
{
  const int wid = (blockIdx.x*blockDim.x + threadIdx.x) >> 6;
  const int lane = threadIdx.x & 63;
  const int gl = lane & 15;
  const int node = wid*4 + (lane >> 4);
  if (node >= N) return;
  const int beg = offs[node], end = offs[node+1];
  const float uni = selfS[node];

  float m = -1e30f, s = 0.f;
  for (int i = beg + gl; i < end; i += 16){
    float a = gS[srtO[i]] + uni;
    a = a > 0.f ? a : 0.2f * a;
    float mn = fmaxf(m, a);
    s = s*__expf(m - mn) + __expf(a - mn);
    m = mn;
  }
  #pragma unroll
  for (int off = 8; off > 0; off >>= 1){        // width-16 merge
    float m2 = __shfl_xor(m, off, 64);
    float s2 = __shfl_xor(s, off, 64);
    float mn = fmaxf(m, m2);
    s = s*__expf(m - mn) + s2*__expf(m2 - mn);
    m = mn;
  }
  const float inv = 1.f / (s + 1e-16f);

  float4 acc0 = make_float4(0.f,0.f,0.f,0.f);
  float4 acc1 = make_float4(0.f,0.f,0.f,0.f);
  const float4* xs4 = (const float4*)xs;
  const int gbase = lane & 48;
  for (int base = beg; base < end; base += 16){
    int i = base + gl;
    int o = 0; float wgt = 0.f;
    if (i < end){
      o = srtO[i];
      float a = gS[o] + uni;
      a = a > 0.f ? a : 0.2f * a;
      wgt = __expf(a - m) * inv;
    }
    int nn = min(16, end - base);
    for (int j = 0; j < nn; ++j){
      int   oo = __shfl(o,   gbase + j, 64);
      float ww = __shfl(wgt, gbase + j, 64);
      float4 v0 = xs4[(oo << 5) + gl];
      float4 v1 = xs4[(oo << 5) + 16 + gl];
      acc0.x += ww*v0.x; acc0.y += ww*v0.y; acc0.z += ww*v0.z; acc0.w += ww*v0.w;
      acc1.x += ww*v1.x; acc1.y += ww*v1.y; acc1.z += ww*v1.z; acc1.w += ww*v1.w;
    }
  }
  float4 b0 = ((const float4*)bias)[gl];
  float4 b1 = ((const float4*)bias)[16 + gl];
  float4 r0 = make_float4(fmaxf(acc0.x+b0.x,0.f), fmaxf(acc0.y+b0.y,0.f),
                          fmaxf(acc0.z+b0.z,0.f), fmaxf(acc0.w+b0.w,0.f));
  float4 r1 = make_float4(fmaxf(acc1.x+b1.x,0.f), fmaxf(acc1.y+b1.y,0.f),
                          fmaxf(acc1.z+b1.z,0.f), fmaxf(acc1.w+b1.w,0.f));
  ((float4*)out)[(node << 5) + gl]      = r0;
  ((float4*)out)[(node << 5) + 16 + gl] = r1;
  if (qd){
    float4 q0 = ((const float4*)qd)[gl];
    float4 q1 = ((const float4*)qd)[16 + gl];
    float p = r0.x*q0.x + r0.y*q0.y + r0.z*q0.z + r0.w*q0.w
            + r1.x*q1.x + r1.y*q1.y + r1.z*q1.z + r1.w*q1.w;
    #pragma unroll
    for (int off = 8; off > 0; off >>= 1) p += __shfl_xor(p, off, 64);
    if (gl == 0) sout[node] = p;
  }
}

// pred[l] = mu_u[label_src[l],:] . mu_d[label_dst[l],:]  (wave per label, O=64)
__global__ void k_pred(const int* __restrict__ ls, const int* __restrict__ ld,
                       const float* __restrict__ mu_u, const float* __restrict__ mu_d,
                       float* __restrict__ pred, int L)
{
  int wid  = (blockIdx.x * blockDim.x + threadIdx.x) >> 6;
  int lane = threadIdx.x & 63;
  if (wid >= L) return;
  float p = mu_u[(ls[wid] << 6) + lane] * mu_d[(ld[wid] << 6) + lane];
  p = wave_reduce_sum(p);
  if (lane == 0) pred[wid] = p;
}

extern "C" void kernel_launch(void* const* d_in, const int* in_sizes, int n_in,
                              void* d_out, int out_size, void* d_ws, size_t ws_size,
                              hipStream_t stream)
{
  (void)n_in; (void)out_size; (void)ws_size;
  const float* x_user    = (const float*)d_in[0];
  const float* x_dest    = (const float*)d_in[1];
  const int*   edge_src  = (const int*)d_in[2];
  const int*   edge_dst  = (const int*)d_in[3];
  const int*   eattr_cat = (const int*)d_in[4];
  const float* eattr_num = (const float*)d_in[5];
  const int*   label_src = (const int*)d_in[6];
  const int*   label_dst = (const int*)d_in[7];
  const float* user_emb  = (const float*)d_in[8];
  const float* dest_emb  = (const float*)d_in[9];
  const float* Wuf = (const float*)d_in[10]; const float* buf_ = (const float*)d_in[11];
  const float* Wdf = (const float*)d_in[12]; const float* bdf  = (const float*)d_in[13];
  const float* emb_acc    = (const float*)d_in[14];
  const float* emb_trans  = (const float*)d_in[15];
  const float* emb_season = (const float*)d_in[16];
  const float* Wnum = (const float*)d_in[17]; const float* bnum  = (const float*)d_in[18];
  const float* Weout = (const float*)d_in[19]; const float* beout = (const float*)d_in[20];
  const float* c1v_Ws = (const float*)d_in[21]; const float* c1v_Wd = (const float*)d_in[22];
  const float* c1v_as = (const float*)d_in[23]; const float* c1v_ad = (const float*)d_in[24];
  const float* c1v_We = (const float*)d_in[25]; const float* c1v_ae = (const float*)d_in[26];
  const float* c1v_b  = (const float*)d_in[27];
  const float* c1r_Ws = (const float*)d_in[28]; const float* c1r_Wd = (const float*)d_in[29];
  const float* c1r_as = (const float*)d_in[30]; const float* c1r_ad = (const float*)d_in[31];
  const float* c1r_b  = (const float*)d_in[32];
  const float* c2v_W  = (const float*)d_in[33]; const float* c2v_as = (const float*)d_in[34];
  const float* c2v_ad = (const float*)d_in[35]; const float* c2v_We = (const float*)d_in[36];
  const float* c2v_ae = (const float*)d_in[37]; const float* c2v_b  = (const float*)d_in[38];
  const float* c2r_W  = (const float*)d_in[39]; const float* c2r_as = (const float*)d_in[40];
  const float* c2r_ad = (const float*)d_in[41]; const float* c2r_b  = (const float*)d_in[42];
  const float* Wmu = (const float*)d_in[43]; const float* bmu = (const float*)d_in[44];
  const float* Wls = (const float*)d_in[45]; const float* bls = (const float*)d_in[46];

  const int U = in_sizes[0] / 3;
  const int D = in_sizes[1];
  const int E = in_sizes[2];
  const int L = in_sizes[6];
  const int O = 64;
  const int nbD = CDIV(D, 1024), nbU = CDIV(U, 1024);

  // ---- workspace layout ----
  float* fw = (float*)d_ws;
  size_t off = 0;
  auto falloc = [&](size_t n)->float*{ float* p = fw + off; off += (n + 3) & ~(size_t)3; return p; };
  float* A    = falloc((size_t)U * H);   // h_user -> hu -> zu
  float* BIG  = falloc((size_t)U * H);   // xs (v-direction payloads)
  float* Bd   = falloc((size_t)D * H);   // h_dest -> hd -> zd
  float* SM   = falloc((size_t)D * H);   // xs (r-direction payloads)
  float* sUa  = falloc(U);               // ssrc (U-indexed, v-dir)
  float* sUb  = falloc(U);               // sdst (U-indexed, r-dir)
  float* sDa  = falloc(D);               // sdst (D-indexed, v-dir)
  float* sDb  = falloc(D);               // ssrc (D-indexed, r-dir)
  float* sml  = falloc(17152);
  int* iw = (int*)(fw + off);
  size_t ioff = 0;
  auto ialloc = [&](size_t n)->int*{ int* p = iw + ioff; ioff += (n + 3) & ~(size_t)3; return p; };
  int* recD  = ialloc((size_t)E * 2);    // int2 records (8B)
  int* srtOU = ialloc(E);
  int* packed= ialloc(E);
  int* cntD  = ialloc(D);
  int* curD  = ialloc(D);
  int* offsD = ialloc((size_t)D + 1);
  int* cntU  = ialloc(U);
  int* curU  = ialloc(U);
  int* offsU = ialloc((size_t)U + 1);
  int* bsumD = ialloc(1024);
  int* bsumU = ialloc(1024);

  float* outp = (float*)d_out;
  float* pred = outp;
  float* mu_u = outp + L;
  float* mu_d = mu_u + (size_t)U * O;
  float* ls_u = mu_d + (size_t)D * O;
  float* ls_d = ls_u + (size_t)U * O;

  // ---- precompute + encoders (fused layer-1 sdst dots) ----
  hipLaunchKernelGGL(k_precompute, dim3(12), dim3(128), 0, stream,
                     c1v_Wd, c1v_ad, c1r_Wd, c1r_ad, c2v_W, c2v_ad, c2r_W, c2r_ad,
                     c1v_We, c1v_ae, c2v_We, c2v_ae, Weout, beout,
                     emb_acc, emb_trans, emb_season, Wnum, bnum, Wmu, Wls, bmu, bls, sml);
  hipLaunchKernelGGL(k_enc_user, dim3(CDIV(U,4)), dim3(256), 0, stream,
                     user_emb, x_user, Wuf, buf_, sml+128, A, sUb, U);
  hipLaunchKernelGGL(k_enc_dest, dim3(CDIV(D,4)), dim3(256), 0, stream,
                     dest_emb, x_dest, Wdf, bdf, sml+0, Bd, sDa, D);

  // ---- CSR build ----
  hipLaunchKernelGGL(k_zero2, dim3(CDIV(U+D,256)), dim3(256), 0, stream, cntU, U, cntD, D);
  hipLaunchKernelGGL(k_pack_count, dim3(CDIV(E,256)), dim3(256), 0, stream,
                     edge_src, edge_dst, eattr_cat, eattr_num, sml+512, sml+576,
                     cntU, cntD, packed, E);
  hipLaunchKernelGGL(k_scan1, dim3(nbD), dim3(1024), 0, stream, cntD, offsD, bsumD, D);
  hipLaunchKernelGGL(k_scan1, dim3(nbU), dim3(1024), 0, stream, cntU, offsU, bsumU, U);
  hipLaunchKernelGGL(k_scan2, dim3(1), dim3(1024), 0, stream, bsumD, nbD);
  hipLaunchKernelGGL(k_scan2, dim3(1), dim3(1024), 0, stream, bsumU, nbU);
  hipLaunchKernelGGL(k_scan3, dim3(CDIV(D,256)), dim3(256), 0, stream, cntD, bsumD, offsD, curD, D);
  hipLaunchKernelGGL(k_scan3, dim3(CDIV(U,256)), dim3(256), 0, stream, cntU, bsumU, offsU, curU, U);
  hipLaunchKernelGGL(k_scatter_binned, dim3(512), dim3(256), 0, stream,
                     edge_src, edge_dst, packed, curU, curD, (int2*)recD, srtOU, E, U, D);

  // ---- layer 1 ----
  hipLaunchKernelGGL(k_gemm128, dim3(CDIV(U,64)), dim3(256), 0, stream,
                     A,  c1v_Ws, (const float*)nullptr, c1v_as, sUa, BIG, BIG+64, 128, 128, U);
  hipLaunchKernelGGL(k_gemm128, dim3(CDIV(D,64)), dim3(256), 0, stream,
                     Bd, c1r_Ws, (const float*)nullptr, c1r_as, sDb, SM, SM+64, 128, 128, D);
  hipLaunchKernelGGL(k_agg_v, dim3(CDIV(D,8)), dim3(256), 0, stream,
                     offsD, (const int2*)recD, sUa, sDa, 0, BIG, c1v_b, Bd, sml+256, sDa, D); // hd (+sdst2v)
  hipLaunchKernelGGL(k_agg_r, dim3(CDIV(U,16)), dim3(256), 0, stream,
                     offsU, srtOU, sDb, sUb, SM, c1r_b, A, sml+384, sUb, U);                  // hu (+sdst2r)

  // ---- layer 2 ----
  hipLaunchKernelGGL(k_gemm128, dim3(CDIV(U,64)), dim3(256), 0, stream,
                     A,  c2v_W, (const float*)nullptr, c2v_as, sUa, BIG, BIG+64, 128, 128, U);
  hipLaunchKernelGGL(k_gemm128, dim3(CDIV(D,64)), dim3(256), 0, stream,
                     Bd, c2r_W, (const float*)nullptr, c2r_as, sDb, SM, SM+64, 128, 128, D);
  hipLaunchKernelGGL(k_agg_v, dim3(CDIV(D,8)), dim3(256), 0, stream,
                     offsD, (const int2*)recD, sUa, sDa, 1, BIG, c2v_b, Bd,
                     (const float*)nullptr, (float*)nullptr, D);                              // zd
  hipLaunchKernelGGL(k_agg_r, dim3(CDIV(U,16)), dim3(256), 0, stream,
                     offsU, srtOU, sDb, sUb, SM, c2r_b, A,
                     (const float*)nullptr, (float*)nullptr, U);                              // zu

  // ---- heads + decode ----
  hipLaunchKernelGGL(k_gemm128, dim3(CDIV(U,64)), dim3(256), 0, stream,
                     A,  sml+768, sml+640, (const float*)nullptr, (float*)nullptr, mu_u, ls_u, 64, 64, U);
  hipLaunchKernelGGL(k_gemm128, dim3(CDIV(D,64)), dim3(256), 0, stream,
                     Bd, sml+768, sml+640, (const float*)nullptr, (float*)nullptr, mu_d, ls_d, 64, 64, D);
  hipLaunchKernelGGL(k_pred, dim3(CDIV((size_t)L*64,256)), dim3(256), 0, stream,
                     label_src, label_dst, mu_u, mu_d, pred, L);
}

// Round 8
// 769.897 us; speedup vs baseline: 1.7620x; 1.0293x over previous
//
#include <hip/hip_runtime.h>
#include <hip/hip_bf16.h>
#include <hip/hip_fp16.h>
#include <math.h>

#define H 128
#define CDIV(a,b) (((a)+(b)-1)/(b))

__device__ __forceinline__ float wave_reduce_sum(float v){
  #pragma unroll
  for (int off = 32; off > 0; off >>= 1) v += __shfl_down(v, off, 64);
  return v;
}

__device__ __forceinline__ float unpack_c(int pk, int lsel){
  unsigned u = (unsigned)pk;
  unsigned short h = (unsigned short)(lsel ? (u >> 16) : (u & 0xffffu));
  return __half2float(__ushort_as_half(h));
}

// ---------------------------------------------------------------------------
// sm layout (floats):
//  [0..127]    qd1v   [128..255] qd1r   [256..383] qd2v   [384..511] qd2r
//  [512..575]  layer1 edge tables: sacc[20] strans[20] sseason[20] wn[3] cb[1]
//  [576..639]  layer2 edge tables
//  [640..767]  biascat = [bmu | bls]
//  [768..17151] Wcat[128][128] = [Wmu | Wls]
// ---------------------------------------------------------------------------
__global__ __launch_bounds__(128) void k_precompute(
    const float* c1v_Wd, const float* c1v_ad,
    const float* c1r_Wd, const float* c1r_ad,
    const float* c2v_W,  const float* c2v_ad,
    const float* c2r_W,  const float* c2r_ad,
    const float* c1v_We, const float* c1v_ae,
    const float* c2v_We, const float* c2v_ae,
    const float* Weout,  const float* beout,
    const float* emb_acc, const float* emb_trans, const float* emb_season,
    const float* Wnum, const float* bnum,
    const float* Wmu, const float* Wls, const float* bmu, const float* bls,
    float* sm)
{
  const int b = blockIdx.x, t = threadIdx.x;
  if (b < 4){
    const float* M; const float* a;
    if      (b == 0){ M = c1v_Wd; a = c1v_ad; }
    else if (b == 1){ M = c1r_Wd; a = c1r_ad; }
    else if (b == 2){ M = c2v_W;  a = c2v_ad; }
    else            { M = c2r_W;  a = c2r_ad; }
    float s = 0.f;
    for (int j = 0; j < H; ++j) s += M[t*H+j] * a[j];
    sm[b*H + t] = s;
  } else if (b == 4){
    __shared__ float ws[H], vs[H];
    for (int layer = 0; layer < 2; ++layer){
      const float* We = layer ? c2v_We : c1v_We;
      const float* ae = layer ? c2v_ae : c1v_ae;
      float w = 0.f;
      for (int j = 0; j < H; ++j) w += We[t*H+j] * ae[j];
      ws[t] = w;
      __syncthreads();
      float v = 0.f;
      for (int j = 0; j < H; ++j) v += Weout[t*H+j] * ws[j];
      vs[t] = v;
      __syncthreads();
      float* tab = sm + 512 + layer*64;
      if (t < 20){
        float s1 = 0.f, s2 = 0.f, s3 = 0.f;
        for (int i = 0; i < 32; ++i){
          s1 += emb_acc   [t*32+i] * vs[i];
          s2 += emb_trans [t*32+i] * vs[32+i];
          s3 += emb_season[t*32+i] * vs[64+i];
        }
        tab[t] = s1; tab[20+t] = s2; tab[40+t] = s3;
      }
      if (t < 3){
        float s = 0.f;
        for (int i = 0; i < 32; ++i) s += Wnum[t*32+i] * vs[96+i];
        tab[60+t] = s;
      }
      if (t == 0){
        float s = 0.f;
        for (int j = 0; j < H; ++j)  s += beout[j] * ws[j];
        for (int i = 0; i < 32; ++i) s += bnum[i] * vs[96+i];
        tab[63] = s;
      }
      __syncthreads();
    }
  } else {
    float* Wcat = sm + 768;
    for (int i = (b-5)*128 + t; i < 8192; i += 7*128){
      int h = i >> 6, o = i & 63;
      Wcat[h*H + o]      = Wmu[h*64 + o];
      Wcat[h*H + 64 + o] = Wls[h*64 + o];
    }
    if (b == 5) sm[640 + t] = (t < 64) ? bmu[t] : bls[t-64];
  }
}

// wave-per-row encoders, fused sdst dot: sout[r] = h[r,:] . qd
__global__ __launch_bounds__(256) void k_enc_user(
    const float* __restrict__ emb, const float* __restrict__ x,
    const float* __restrict__ Wf, const float* __restrict__ b,
    const float* __restrict__ qd, float* __restrict__ out,
    float* __restrict__ sout, int N)
{
  int w = (blockIdx.x*blockDim.x + threadIdx.x) >> 6;
  int lane = threadIdx.x & 63;
  if (w >= N) return;
  float2 e  = ((const float2*)emb)[(size_t)w*64 + lane];
  float x0 = x[w*3], x1 = x[w*3+1], x2 = x[w*3+2];
  float2 w0 = ((const float2*)Wf)[lane];
  float2 w1 = ((const float2*)Wf)[64+lane];
  float2 w2 = ((const float2*)Wf)[128+lane];
  float2 bb = ((const float2*)b)[lane];
  float h0 = e.x + bb.x + x0*w0.x + x1*w1.x + x2*w2.x;
  float h1 = e.y + bb.y + x0*w0.y + x1*w1.y + x2*w2.y;
  ((float2*)out)[(size_t)w*64 + lane] = make_float2(h0, h1);
  float2 q = ((const float2*)qd)[lane];
  float p = wave_reduce_sum(h0*q.x + h1*q.y);
  if (lane == 0) sout[w] = p;
}

__global__ __launch_bounds__(256) void k_enc_dest(
    const float* __restrict__ emb, const float* __restrict__ x,
    const float* __restrict__ Wf, const float* __restrict__ b,
    const float* __restrict__ qd, float* __restrict__ out,
    float* __restrict__ sout, int N)
{
  int w = (blockIdx.x*blockDim.x + threadIdx.x) >> 6;
  int lane = threadIdx.x & 63;
  if (w >= N) return;
  float2 e  = ((const float2*)emb)[(size_t)w*64 + lane];
  float x0 = x[w];
  float2 w0 = ((const float2*)Wf)[lane];
  float2 bb = ((const float2*)b)[lane];
  float h0 = e.x + bb.x + x0*w0.x;
  float h1 = e.y + bb.y + x0*w0.y;
  ((float2*)out)[(size_t)w*64 + lane] = make_float2(h0, h1);
  float2 q = ((const float2*)qd)[lane];
  float p = wave_reduce_sum(h0*q.x + h1*q.y);
  if (lane == 0) sout[w] = p;
}

// C[N,128] = A[N,128] @ W[128,128] (+bias). cols 0..63 -> out0, 64..127 -> out1.
// 256 threads, 64 rows/block, 4x8 register tile, BK=32 (25.6KB LDS -> 5-6 blk/CU).
__global__ __launch_bounds__(256) void k_gemm128(
    const float* __restrict__ A, const float* __restrict__ W,
    const float* __restrict__ bias, const float* __restrict__ asv,
    float* __restrict__ sout,
    float* __restrict__ out0, float* __restrict__ out1,
    int ld0, int ld1, int N)
{
  __shared__ float Ws[32][128];
  __shared__ float Xs[64][36];          // stride 36: tr-read 2-way (free)
  const int tid = threadIdx.x;
  const int rb  = blockIdx.x * 64;
  const int tc  = tid & 15, tr = tid >> 4;
  const int c0  = tc * 8;
  float C[4][8] = {};
  for (int k0 = 0; k0 < 128; k0 += 32){
    #pragma unroll
    for (int i = tid; i < 1024; i += 256){            // W chunk 32x128 (4 f4/thread)
      int k = i >> 5, c4 = i & 31;
      *(float4*)&Ws[k][c4*4] = *(const float4*)&W[(size_t)(k0+k)*128 + c4*4];
    }
    #pragma unroll
    for (int i = tid; i < 512; i += 256){             // X chunk 64x32 (2 f4/thread)
      int r = i >> 3, kg = i & 7;
      int row = rb + r;
      float4 v = make_float4(0.f,0.f,0.f,0.f);
      if (row < N) v = *(const float4*)&A[(size_t)row*128 + k0 + kg*4];
      *(float4*)&Xs[r][kg*4] = v;
    }
    __syncthreads();
    #pragma unroll 4
    for (int k = 0; k < 32; ++k){
      float4 w0 = *(float4*)&Ws[k][c0];
      float4 w1 = *(float4*)&Ws[k][c0+4];
      #pragma unroll
      for (int i = 0; i < 4; ++i){
        float x = Xs[tr*4+i][k];
        C[i][0] += x*w0.x; C[i][1] += x*w0.y; C[i][2] += x*w0.z; C[i][3] += x*w0.w;
        C[i][4] += x*w1.x; C[i][5] += x*w1.y; C[i][6] += x*w1.z; C[i][7] += x*w1.w;
      }
    }
    __syncthreads();
  }
  float4 b0 = make_float4(0,0,0,0), b1 = make_float4(0,0,0,0);
  if (bias){ b0 = *(const float4*)&bias[c0]; b1 = *(const float4*)&bias[c0+4]; }
  float4 a0 = make_float4(0,0,0,0), a1 = make_float4(0,0,0,0);
  if (asv){ a0 = *(const float4*)&asv[c0]; a1 = *(const float4*)&asv[c0+4]; }
  #pragma unroll
  for (int i = 0; i < 4; ++i){
    int row = rb + tr*4 + i;
    float s = 0.f;
    if (row < N){
      float4 v0 = make_float4(C[i][0]+b0.x, C[i][1]+b0.y, C[i][2]+b0.z, C[i][3]+b0.w);
      float4 v1 = make_float4(C[i][4]+b1.x, C[i][5]+b1.y, C[i][6]+b1.z, C[i][7]+b1.w);
      if (c0 < 64){
        *(float4*)&out0[(size_t)row*ld0 + c0]     = v0;
        *(float4*)&out0[(size_t)row*ld0 + c0 + 4] = v1;
      } else {
        *(float4*)&out1[(size_t)row*ld1 + (c0-64)]     = v0;
        *(float4*)&out1[(size_t)row*ld1 + (c0-64) + 4] = v1;
      }
      if (asv){
        s = C[i][0]*a0.x + C[i][1]*a0.y + C[i][2]*a0.z + C[i][3]*a0.w
          + C[i][4]*a1.x + C[i][5]*a1.y + C[i][6]*a1.z + C[i][7]*a1.w;
      }
    }
    if (asv){
      #pragma unroll
      for (int off = 8; off > 0; off >>= 1) s += __shfl_down(s, off, 16);
      if (tc == 0 && row < N) sout[row] = s;
    }
  }
}

__global__ void k_zero2(int* a, int na, int* b, int nb){
  int i = blockIdx.x * blockDim.x + threadIdx.x;
  if (i < na) a[i] = 0;
  else if (i - na < nb) b[i - na] = 0;
}

// count both degrees + pack per-edge consts for both layers into 4B
__global__ __launch_bounds__(256) void k_pack_count(
    const int* __restrict__ esrc, const int* __restrict__ edst,
    const int* __restrict__ ecat, const float* __restrict__ enum_,
    const float* __restrict__ tab1, const float* __restrict__ tab2,
    int* __restrict__ cntU, int* __restrict__ cntD,
    int* __restrict__ packed, int E)
{
  int e = blockIdx.x * blockDim.x + threadIdx.x;
  if (e >= E) return;
  int c0 = ecat[e*3], c1i = ecat[e*3+1], c2i = ecat[e*3+2];
  float n0 = enum_[e*3], n1 = enum_[e*3+1], n2 = enum_[e*3+2];
  float cA = tab1[c0] + tab1[20+c1i] + tab1[40+c2i]
           + n0*tab1[60] + n1*tab1[61] + n2*tab1[62] + tab1[63];
  float cB = tab2[c0] + tab2[20+c1i] + tab2[40+c2i]
           + n0*tab2[60] + n1*tab2[61] + n2*tab2[62] + tab2[63];
  unsigned ua = __half_as_ushort(__float2half_rn(cA));
  unsigned ub = __half_as_ushort(__float2half_rn(cB));
  packed[e] = (int)((ub << 16) | ua);
  atomicAdd(&cntU[esrc[e]], 1);
  atomicAdd(&cntD[edst[e]], 1);
}

// 3-phase scan
__global__ __launch_bounds__(1024) void k_scan1(const int* __restrict__ cnt,
                                                int* __restrict__ offs,
                                                int* __restrict__ bsum, int n)
{
  __shared__ int wsum[16];
  const int tid = threadIdx.x, lane = tid & 63, wid = tid >> 6;
  const int i = blockIdx.x * 1024 + tid;
  int v = (i < n) ? cnt[i] : 0;
  int inc = v;
  #pragma unroll
  for (int d = 1; d < 64; d <<= 1){
    int t2 = __shfl_up(inc, d, 64);
    if (lane >= d) inc += t2;
  }
  if (lane == 63) wsum[wid] = inc;
  __syncthreads();
  if (tid < 16){
    int x = wsum[tid];
    #pragma unroll
    for (int d = 1; d < 16; d <<= 1){
      int t2 = __shfl_up(x, d, 16);
      if (tid >= d) x += t2;
    }
    wsum[tid] = x;
  }
  __syncthreads();
  int incl = ((wid > 0) ? wsum[wid-1] : 0) + inc;
  if (i < n) offs[i+1] = incl;
  if (tid == 0) bsum[blockIdx.x] = wsum[15];
}

__global__ __launch_bounds__(1024) void k_scan2(int* __restrict__ bsum, int nb)
{
  __shared__ int wsum[16];
  const int tid = threadIdx.x, lane = tid & 63, wid = tid >> 6;
  int v = (tid < nb) ? bsum[tid] : 0;
  int inc = v;
  #pragma unroll
  for (int d = 1; d < 64; d <<= 1){
    int t2 = __shfl_up(inc, d, 64);
    if (lane >= d) inc += t2;
  }
  if (lane == 63) wsum[wid] = inc;
  __syncthreads();
  if (tid < 16){
    int x = wsum[tid];
    #pragma unroll
    for (int d = 1; d < 16; d <<= 1){
      int t2 = __shfl_up(x, d, 16);
      if (tid >= d) x += t2;
    }
    wsum[tid] = x;
  }
  __syncthreads();
  int excl = ((wid > 0) ? wsum[wid-1] : 0) + inc - v;
  if (tid < nb) bsum[tid] = excl;
}

__global__ void k_scan3(const int* __restrict__ cnt, const int* __restrict__ bsum,
                        int* __restrict__ offs, int* __restrict__ cursor, int n)
{
  int i = blockIdx.x * blockDim.x + threadIdx.x;
  if (i >= n) return;
  int v = offs[i+1] + bsum[i >> 10];
  offs[i+1] = v;
  cursor[i] = v - cnt[i];
  if (i == 0) offs[0] = 0;
}

// XCD-binned scatter (see round-7 notes): group (blockIdx&7) owns 1/8 of the
// dst/src ranges so slice writes coalesce in one XCD's L2.
__global__ __launch_bounds__(256) void k_scatter_binned(
    const int* __restrict__ esrc, const int* __restrict__ edst,
    const int* __restrict__ packed,
    int* __restrict__ curU, int* __restrict__ curD,
    int2* __restrict__ recD, int* __restrict__ srtOU, int E, int U, int D)
{
  const int grp = blockIdx.x & 7;
  const int lb  = blockIdx.x >> 3;
  const int GB  = gridDim.x >> 3;
  const int D8 = CDIV(D, 8), U8 = CDIV(U, 8);
  const int dlo = grp * D8, dhi = min(D, dlo + D8);
  const int slo = grp * U8, shi = min(U, slo + U8);
  for (int e = lb*256 + threadIdx.x; e < E; e += GB*256){
    int s = esrc[e], d = edst[e];
    if (d >= dlo && d < dhi){
      int p = atomicAdd(&curD[d], 1);
      recD[p] = make_int2(s, packed[e]);
    }
    if (s >= slo && s < shi){
      int p = atomicAdd(&curU[s], 1);
      srtOU[p] = d;
    }
  }
}

// v-direction GAT aggregate: 32 lanes per node, 2 nodes per wave.
__global__ __launch_bounds__(256) void k_agg_v(
    const int* __restrict__ offs, const int2* __restrict__ rec,
    const float* __restrict__ gS, const float* __restrict__ selfS, int lsel,
    const float* __restrict__ xs, const float* __restrict__ bias,
    float* __restrict__ out, const float* __restrict__ qd,
    float* __restrict__ sout, int N)
{
  const int wid = (blockIdx.x*blockDim.x + threadIdx.x) >> 6;
  const int lane = threadIdx.x & 63;
  const int gl = lane & 31;
  const int node = wid*2 + (lane >> 5);
  if (node >= N) return;
  const int beg = offs[node], end = offs[node+1];
  const float uni = selfS[node];

  float m = -1e30f, s = 0.f;
  for (int i = beg + gl; i < end; i += 32){
    int2 r = rec[i];
    float a = gS[r.x] + uni + unpack_c(r.y, lsel);
    a = a > 0.f ? a : 0.2f * a;
    float mn = fmaxf(m, a);
    s = s*__expf(m - mn) + __expf(a - mn);
    m = mn;
  }
  #pragma unroll
  for (int off = 16; off > 0; off >>= 1){
    float m2 = __shfl_xor(m, off, 64);
    float s2 = __shfl_xor(s, off, 64);
    float mn = fmaxf(m, m2);
    s = s*__expf(m - mn) + s2*__expf(m2 - mn);
    m = mn;
  }
  const float inv = 1.f / (s + 1e-16f);

  float4 acc = make_float4(0.f,0.f,0.f,0.f);
  const float4* xs4 = (const float4*)xs;
  const int gbase = lane & 32;
  for (int base = beg; base < end; base += 32){
    int i = base + gl;
    int o = 0; float wgt = 0.f;
    if (i < end){
      int2 r = rec[i];
      o = r.x;
      float a = gS[o] + uni + unpack_c(r.y, lsel);
      a = a > 0.f ? a : 0.2f * a;
      wgt = __expf(a - m) * inv;
    }
    int nn = min(32, end - base);
    for (int j = 0; j < nn; ++j){
      int   oo = __shfl(o,   gbase + j, 64);
      float ww = __shfl(wgt, gbase + j, 64);
      float4 v = xs4[(oo << 5) + gl];
      acc.x += ww*v.x; acc.y += ww*v.y; acc.z += ww*v.z; acc.w += ww*v.w;
    }
  }
  float4 bb = ((const float4*)bias)[gl];
  float4 r4 = make_float4(fmaxf(acc.x+bb.x,0.f), fmaxf(acc.y+bb.y,0.f),
                          fmaxf(acc.z+bb.z,0.f), fmaxf(acc.w+bb.w,0.f));
  ((float4*)out)[(node << 5) + gl] = r4;
  if (qd){
    float4 q4 = ((const float4*)qd)[gl];
    float p = r4.x*q4.x + r4.y*q4.y + r4.z*q4.z + r4.w*q4.w;
    #pragma unroll
    for (int off = 16; off > 0; off >>= 1) p += __shfl_xor(p, off, 64);
    if (gl == 0) sout[node] = p;
  }
}

// r-direction: 16 lanes per node, 4 nodes per wave.
__global__ __launch_bounds__(256) void k_agg_r(
    const int* __restrict__ offs, const int* __restrict__ srtO,
    const float* __restrict__ gS, const float* __restrict__ selfS,
    const float* __restrict__ xs, const float* __restrict__ bias,
    float* __restrict__ out, const float* __restrict__ qd,
    float* __restrict__ sout, int N)
{
  const int wid = (blockIdx.x*blockDim.x + threadIdx.x) >> 6;
  const int lane = threadIdx.x & 63;
  const int gl = lane & 15;
  const int node = wid*4 + (lane >> 4);
  if (node >= N) return;
  const int beg = offs[node], end = offs[node+1];
  const float uni = selfS[node];

  float m = -1e30f, s = 0.f;
  for (int i = beg + gl; i < end; i += 16){
    float a = gS[srtO[i]] + uni;
    a = a > 0.f ? a : 0.2f * a;
    float mn = fmaxf(m, a);
    s = s*__expf(m - mn) + __expf(a - mn);
    m = mn;
  }
  #pragma unroll
  for (int off = 8; off > 0; off >>= 1){
    float m2 = __shfl_xor(m, off, 64);
    float s2 = __shfl_xor(s, off, 64);
    float mn = fmaxf(m, m2);
    s = s*__expf(m - mn) + s2*__expf(m2 - mn);
    m = mn;
  }
  const float inv = 1.f / (s + 1e-16f);

  float4 acc0 = make_float4(0.f,0.f,0.f,0.f);
  float4 acc1 = make_float4(0.f,0.f,0.f,0.f);
  const float4* xs4 = (const float4*)xs;
  const int gbase = lane & 48;
  for (int base = beg; base < end; base += 16){
    int i = base + gl;
    int o = 0; float wgt = 0.f;
    if (i < end){
      o = srtO[i];
      float a = gS[o] + uni;
      a = a > 0.f ? a : 0.2f * a;
      wgt = __expf(a - m) * inv;
    }
    int nn = min(16, end - base);
    for (int j = 0; j < nn; ++j){
      int   oo = __shfl(o,   gbase + j, 64);
      float ww = __shfl(wgt, gbase + j, 64);
      float4 v0 = xs4[(oo << 5) + gl];
      float4 v1 = xs4[(oo << 5) + 16 + gl];
      acc0.x += ww*v0.x; acc0.y += ww*v0.y; acc0.z += ww*v0.z; acc0.w += ww*v0.w;
      acc1.x += ww*v1.x; acc1.y += ww*v1.y; acc1.z += ww*v1.z; acc1.w += ww*v1.w;
    }
  }
  float4 b0 = ((const float4*)bias)[gl];
  float4 b1 = ((const float4*)bias)[16 + gl];
  float4 r0 = make_float4(fmaxf(acc0.x+b0.x,0.f), fmaxf(acc0.y+b0.y,0.f),
                          fmaxf(acc0.z+b0.z,0.f), fmaxf(acc0.w+b0.w,0.f));
  float4 r1 = make_float4(fmaxf(acc1.x+b1.x,0.f), fmaxf(acc1.y+b1.y,0.f),
                          fmaxf(acc1.z+b1.z,0.f), fmaxf(acc1.w+b1.w,0.f));
  ((float4*)out)[(node << 5) + gl]      = r0;
  ((float4*)out)[(node << 5) + 16 + gl] = r1;
  if (qd){
    float4 q0 = ((const float4*)qd)[gl];
    float4 q1 = ((const float4*)qd)[16 + gl];
    float p = r0.x*q0.x + r0.y*q0.y + r0.z*q0.z + r0.w*q0.w
            + r1.x*q1.x + r1.y*q1.y + r1.z*q1.z + r1.w*q1.w;
    #pragma unroll
    for (int off = 8; off > 0; off >>= 1) p += __shfl_xor(p, off, 64);
    if (gl == 0) sout[node] = p;
  }
}

// pred[l] = mu_u[label_src[l],:] . mu_d[label_dst[l],:]  (wave per label, O=64)
__global__ void k_pred(const int* __restrict__ ls, const int* __restrict__ ld,
                       const float* __restrict__ mu_u, const float* __restrict__ mu_d,
                       float* __restrict__ pred, int L)
{
  int wid  = (blockIdx.x * blockDim.x + threadIdx.x) >> 6;
  int lane = threadIdx.x & 63;
  if (wid >= L) return;
  float p = mu_u[(ls[wid] << 6) + lane] * mu_d[(ld[wid] << 6) + lane];
  p = wave_reduce_sum(p);
  if (lane == 0) pred[wid] = p;
}

extern "C" void kernel_launch(void* const* d_in, const int* in_sizes, int n_in,
                              void* d_out, int out_size, void* d_ws, size_t ws_size,
                              hipStream_t stream)
{
  (void)n_in; (void)out_size; (void)ws_size;
  const float* x_user    = (const float*)d_in[0];
  const float* x_dest    = (const float*)d_in[1];
  const int*   edge_src  = (const int*)d_in[2];
  const int*   edge_dst  = (const int*)d_in[3];
  const int*   eattr_cat = (const int*)d_in[4];
  const float* eattr_num = (const float*)d_in[5];
  const int*   label_src = (const int*)d_in[6];
  const int*   label_dst = (const int*)d_in[7];
  const float* user_emb  = (const float*)d_in[8];
  const float* dest_emb  = (const float*)d_in[9];
  const float* Wuf = (const float*)d_in[10]; const float* buf_ = (const float*)d_in[11];
  const float* Wdf = (const float*)d_in[12]; const float* bdf  = (const float*)d_in[13];
  const float* emb_acc    = (const float*)d_in[14];
  const float* emb_trans  = (const float*)d_in[15];
  const float* emb_season = (const float*)d_in[16];
  const float* Wnum = (const float*)d_in[17]; const float* bnum  = (const float*)d_in[18];
  const float* Weout = (const float*)d_in[19]; const float* beout = (const float*)d_in[20];
  const float* c1v_Ws = (const float*)d_in[21]; const float* c1v_Wd = (const float*)d_in[22];
  const float* c1v_as = (const float*)d_in[23]; const float* c1v_ad = (const float*)d_in[24];
  const float* c1v_We = (const float*)d_in[25]; const float* c1v_ae = (const float*)d_in[26];
  const float* c1v_b  = (const float*)d_in[27];
  const float* c1r_Ws = (const float*)d_in[28]; const float* c1r_Wd = (const float*)d_in[29];
  const float* c1r_as = (const float*)d_in[30]; const float* c1r_ad = (const float*)d_in[31];
  const float* c1r_b  = (const float*)d_in[32];
  const float* c2v_W  = (const float*)d_in[33]; const float* c2v_as = (const float*)d_in[34];
  const float* c2v_ad = (const float*)d_in[35]; const float* c2v_We = (const float*)d_in[36];
  const float* c2v_ae = (const float*)d_in[37]; const float* c2v_b  = (const float*)d_in[38];
  const float* c2r_W  = (const float*)d_in[39]; const float* c2r_as = (const float*)d_in[40];
  const float* c2r_ad = (const float*)d_in[41]; const float* c2r_b  = (const float*)d_in[42];
  const float* Wmu = (const float*)d_in[43]; const float* bmu = (const float*)d_in[44];
  const float* Wls = (const float*)d_in[45]; const float* bls = (const float*)d_in[46];

  const int U = in_sizes[0] / 3;
  const int D = in_sizes[1];
  const int E = in_sizes[2];
  const int L = in_sizes[6];
  const int O = 64;
  const int nbD = CDIV(D, 1024), nbU = CDIV(U, 1024);

  // ---- workspace layout ----
  float* fw = (float*)d_ws;
  size_t off = 0;
  auto falloc = [&](size_t n)->float*{ float* p = fw + off; off += (n + 3) & ~(size_t)3; return p; };
  float* A    = falloc((size_t)U * H);   // h_user -> hu -> zu
  float* BIG  = falloc((size_t)U * H);   // xs (v-direction payloads)
  float* Bd   = falloc((size_t)D * H);   // h_dest -> hd -> zd
  float* SM   = falloc((size_t)D * H);   // xs (r-direction payloads)
  float* sUa  = falloc(U);               // ssrc (U-indexed, v-dir)
  float* sUb  = falloc(U);               // sdst (U-indexed, r-dir)
  float* sDa  = falloc(D);               // sdst (D-indexed, v-dir)
  float* sDb  = falloc(D);               // ssrc (D-indexed, r-dir)
  float* sml  = falloc(17152);
  int* iw = (int*)(fw + off);
  size_t ioff = 0;
  auto ialloc = [&](size_t n)->int*{ int* p = iw + ioff; ioff += (n + 3) & ~(size_t)3; return p; };
  int* recD  = ialloc((size_t)E * 2);    // int2 records (8B)
  int* srtOU = ialloc(E);
  int* packed= ialloc(E);
  int* cntD  = ialloc(D);
  int* curD  = ialloc(D);
  int* offsD = ialloc((size_t)D + 1);
  int* cntU  = ialloc(U);
  int* curU  = ialloc(U);
  int* offsU = ialloc((size_t)U + 1);
  int* bsumD = ialloc(1024);
  int* bsumU = ialloc(1024);

  float* outp = (float*)d_out;
  float* pred = outp;
  float* mu_u = outp + L;
  float* mu_d = mu_u + (size_t)U * O;
  float* ls_u = mu_d + (size_t)D * O;
  float* ls_d = ls_u + (size_t)U * O;

  // ---- precompute + encoders (fused layer-1 sdst dots) ----
  hipLaunchKernelGGL(k_precompute, dim3(12), dim3(128), 0, stream,
                     c1v_Wd, c1v_ad, c1r_Wd, c1r_ad, c2v_W, c2v_ad, c2r_W, c2r_ad,
                     c1v_We, c1v_ae, c2v_We, c2v_ae, Weout, beout,
                     emb_acc, emb_trans, emb_season, Wnum, bnum, Wmu, Wls, bmu, bls, sml);
  hipLaunchKernelGGL(k_enc_user, dim3(CDIV(U,4)), dim3(256), 0, stream,
                     user_emb, x_user, Wuf, buf_, sml+128, A, sUb, U);
  hipLaunchKernelGGL(k_enc_dest, dim3(CDIV(D,4)), dim3(256), 0, stream,
                     dest_emb, x_dest, Wdf, bdf, sml+0, Bd, sDa, D);

  // ---- CSR build ----
  hipLaunchKernelGGL(k_zero2, dim3(CDIV(U+D,256)), dim3(256), 0, stream, cntU, U, cntD, D);
  hipLaunchKernelGGL(k_pack_count, dim3(CDIV(E,256)), dim3(256), 0, stream,
                     edge_src, edge_dst, eattr_cat, eattr_num, sml+512, sml+576,
                     cntU, cntD, packed, E);
  hipLaunchKernelGGL(k_scan1, dim3(nbD), dim3(1024), 0, stream, cntD, offsD, bsumD, D);
  hipLaunchKernelGGL(k_scan1, dim3(nbU), dim3(1024), 0, stream, cntU, offsU, bsumU, U);
  hipLaunchKernelGGL(k_scan2, dim3(1), dim3(1024), 0, stream, bsumD, nbD);
  hipLaunchKernelGGL(k_scan2, dim3(1), dim3(1024), 0, stream, bsumU, nbU);
  hipLaunchKernelGGL(k_scan3, dim3(CDIV(D,256)), dim3(256), 0, stream, cntD, bsumD, offsD, curD, D);
  hipLaunchKernelGGL(k_scan3, dim3(CDIV(U,256)), dim3(256), 0, stream, cntU, bsumU, offsU, curU, U);
  hipLaunchKernelGGL(k_scatter_binned, dim3(512), dim3(256), 0, stream,
                     edge_src, edge_dst, packed, curU, curD, (int2*)recD, srtOU, E, U, D);

  // ---- layer 1 ----
  hipLaunchKernelGGL(k_gemm128, dim3(CDIV(U,64)), dim3(256), 0, stream,
                     A,  c1v_Ws, (const float*)nullptr, c1v_as, sUa, BIG, BIG+64, 128, 128, U);
  hipLaunchKernelGGL(k_gemm128, dim3(CDIV(D,64)), dim3(256), 0, stream,
                     Bd, c1r_Ws, (const float*)nullptr, c1r_as, sDb, SM, SM+64, 128, 128, D);
  hipLaunchKernelGGL(k_agg_v, dim3(CDIV(D,8)), dim3(256), 0, stream,
                     offsD, (const int2*)recD, sUa, sDa, 0, BIG, c1v_b, Bd, sml+256, sDa, D); // hd (+sdst2v)
  hipLaunchKernelGGL(k_agg_r, dim3(CDIV(U,16)), dim3(256), 0, stream,
                     offsU, srtOU, sDb, sUb, SM, c1r_b, A, sml+384, sUb, U);                  // hu (+sdst2r)

  // ---- layer 2 ----
  hipLaunchKernelGGL(k_gemm128, dim3(CDIV(U,64)), dim3(256), 0, stream,
                     A,  c2v_W, (const float*)nullptr, c2v_as, sUa, BIG, BIG+64, 128, 128, U);
  hipLaunchKernelGGL(k_gemm128, dim3(CDIV(D,64)), dim3(256), 0, stream,
                     Bd, c2r_W, (const float*)nullptr, c2r_as, sDb, SM, SM+64, 128, 128, D);
  hipLaunchKernelGGL(k_agg_v, dim3(CDIV(D,8)), dim3(256), 0, stream,
                     offsD, (const int2*)recD, sUa, sDa, 1, BIG, c2v_b, Bd,
                     (const float*)nullptr, (float*)nullptr, D);                              // zd
  hipLaunchKernelGGL(k_agg_r, dim3(CDIV(U,16)), dim3(256), 0, stream,
                     offsU, srtOU, sDb, sUb, SM, c2r_b, A,
                     (const float*)nullptr, (float*)nullptr, U);                              // zu

  // ---- heads + decode ----
  hipLaunchKernelGGL(k_gemm128, dim3(CDIV(U,64)), dim3(256), 0, stream,
                     A,  sml+768, sml+640, (const float*)nullptr, (float*)nullptr, mu_u, ls_u, 64, 64, U);
  hipLaunchKernelGGL(k_gemm128, dim3(CDIV(D,64)), dim3(256), 0, stream,
                     Bd, sml+768, sml+640, (const float*)nullptr, (float*)nullptr, mu_d, ls_d, 64, 64, D);
  hipLaunchKernelGGL(k_pred, dim3(CDIV((size_t)L*64,256)), dim3(256), 0, stream,
                     label_src, label_dst, mu_u, mu_d, pred, L);
}